// Round 2
// baseline (1797.971 us; speedup 1.0000x reference)
//
#include <hip/hip_runtime.h>

// Problem constants
#define Bq 4
#define Tq 1024
#define Cq 1024
#define Hq 16
#define Dq 64
#define Fq 4096
#define Lq 4
#define BT (Bq*Tq)

typedef __attribute__((ext_vector_type(8))) __bf16 bf16x8;
typedef __attribute__((ext_vector_type(4))) float  floatx4;

__device__ __forceinline__ unsigned short f2bf(float f) {
  unsigned int u = __builtin_bit_cast(unsigned int, f);
  u = (u + 0x7FFFu + ((u >> 16) & 1u)) >> 16;   // RNE
  return (unsigned short)u;
}

// async global->LDS, 16B per lane; lds ptr must be wave-uniform (HW adds lane*16)
__device__ __forceinline__ void gld_lds16(const void* g, void* lds) {
  __builtin_amdgcn_global_load_lds(
      (const __attribute__((address_space(1))) unsigned int*)g,
      (__attribute__((address_space(3))) unsigned int*)lds, 16, 0, 0);
}

// ---------------- embed: x = concat(emb[acts], dur) + pos ----------------
__global__ __launch_bounds__(256) void embed_kernel(
    const int* __restrict__ acts, const float* __restrict__ dur,
    const float* __restrict__ emb, const float* __restrict__ pos,
    float* __restrict__ x)
{
  int tok = blockIdx.x;
  int t = tok & (Tq-1);
  int a = acts[tok];
  const float* er = emb + (size_t)a * (Cq-1);
  const float* pr = pos + (size_t)t * Cq;
  float* xr = x + (size_t)tok * Cq;
  float dv = dur[tok];
  for (int c = threadIdx.x; c < Cq; c += 256) {
    float v = (c < Cq-1) ? er[c] : dv;
    xr[c] = v + pr[c];
  }
}

// ---------------- rmsnorm -> bf16 ----------------
__global__ __launch_bounds__(256) void rmsnorm_kernel(
    const float* __restrict__ x, const float* __restrict__ g,
    unsigned short* __restrict__ h)
{
  int tok = blockIdx.x, tid = threadIdx.x;
  const float4* xr = (const float4*)(x + (size_t)tok * Cq);
  float4 v = xr[tid];
  float ss = v.x*v.x + v.y*v.y + v.z*v.z + v.w*v.w;
  #pragma unroll
  for (int s = 32; s >= 1; s >>= 1) ss += __shfl_xor(ss, s, 64);
  __shared__ float ws4[4];
  if ((tid & 63) == 0) ws4[tid >> 6] = ss;
  __syncthreads();
  float tot = ws4[0] + ws4[1] + ws4[2] + ws4[3];
  float r = rsqrtf(tot * (1.0f/(float)Cq) + 1.1920928955078125e-07f);
  float4 gv = ((const float4*)g)[tid];
  unsigned short o4[4] = { f2bf(v.x*r*gv.x), f2bf(v.y*r*gv.y),
                           f2bf(v.z*r*gv.z), f2bf(v.w*r*gv.w) };
  *(uint2*)(h + (size_t)tok*Cq + tid*4) = *(const uint2*)o4;
}

// ---------------- transpose + cast: in (z batches of R x Cc) f32 -> out (Cc x R) bf16 ----------------
__global__ void transpose_cast_kernel(
    const float* __restrict__ in, unsigned short* __restrict__ out,
    int R, int Cc, int nb2, long long ostr1, long long ostr2)
{
  __shared__ float tile[32][33];
  int c0 = blockIdx.x * 32, r0 = blockIdx.y * 32;
  int tx = threadIdx.x, ty = threadIdx.y;  // 32 x 8
  int z = blockIdx.z;
  const float* ip = in + (size_t)z * R * Cc;
  #pragma unroll
  for (int i = 0; i < 32; i += 8)
    tile[ty+i][tx] = ip[(size_t)(r0+ty+i)*Cc + c0 + tx];
  __syncthreads();
  unsigned short* op = out + (size_t)(z / nb2) * ostr1 + (size_t)(z % nb2) * ostr2;
  #pragma unroll
  for (int i = 0; i < 32; i += 8)
    op[(size_t)(c0+ty+i)*R + r0 + tx] = f2bf(tile[tx][ty+i]);
}

// ---------------- GEMM: C(M,N) = A(M,K) @ Bt(N,K)^T, bf16 in, fp32 acc ----------------
// EPI 0: qkv scatter (q,k -> qkbuf bf16 ldc=2048; v -> vT[b][h][d][t])
// EPI 1: bf16 store of gelu(acc + bias)
// EPI 2: outF += acc + bias  (fp32 residual add)
template <int EPI>
__global__ __launch_bounds__(256)
void gemm_bt_kernel(const unsigned short* __restrict__ A, int lda,
                    const unsigned short* __restrict__ Bt, int ldb,
                    int K,
                    unsigned short* __restrict__ outB, int ldc,
                    unsigned short* __restrict__ vT,
                    float* __restrict__ outF, int ldf,
                    const float* __restrict__ bias)
{
  __shared__ unsigned short lds_a[128*32];
  __shared__ unsigned short lds_b[128*32];
  int tid = threadIdx.x;
  int lane = tid & 63, wv = tid >> 6;
  int lane15 = lane & 15, laneh = lane >> 4;
  int m0 = blockIdx.y * 128, n0 = blockIdx.x * 128;
  int wm = wv & 1, wn = wv >> 1;

  floatx4 acc[4][4];
  #pragma unroll
  for (int i = 0; i < 4; i++)
    #pragma unroll
    for (int j = 0; j < 4; j++) acc[i][j] = (floatx4){0.f,0.f,0.f,0.f};

  int seg0 = (wv*2+0)*64 + lane;
  int seg1 = (wv*2+1)*64 + lane;
  int ra0 = seg0 >> 2, ca0 = (seg0 & 3) * 8;
  int ra1 = seg1 >> 2, ca1 = (seg1 & 3) * 8;
  const unsigned short* a_src0 = A  + (size_t)(m0+ra0)*lda + ca0;
  const unsigned short* a_src1 = A  + (size_t)(m0+ra1)*lda + ca1;
  const unsigned short* b_src0 = Bt + (size_t)(n0+ra0)*ldb + ca0;
  const unsigned short* b_src1 = Bt + (size_t)(n0+ra1)*ldb + ca1;
  unsigned short* a_dst0 = &lds_a[(wv*2+0)*512];
  unsigned short* a_dst1 = &lds_a[(wv*2+1)*512];
  unsigned short* b_dst0 = &lds_b[(wv*2+0)*512];
  unsigned short* b_dst1 = &lds_b[(wv*2+1)*512];

  for (int k0 = 0; k0 < K; k0 += 32) {
    __syncthreads();
    gld_lds16(a_src0 + k0, a_dst0);
    gld_lds16(a_src1 + k0, a_dst1);
    gld_lds16(b_src0 + k0, b_dst0);
    gld_lds16(b_src1 + k0, b_dst1);
    __syncthreads();
    bf16x8 af[4], bf[4];
    #pragma unroll
    for (int i = 0; i < 4; i++)
      af[i] = *(const bf16x8*)&lds_a[(wm*64 + i*16 + lane15)*32 + laneh*8];
    #pragma unroll
    for (int j = 0; j < 4; j++)
      bf[j] = *(const bf16x8*)&lds_b[(wn*64 + j*16 + lane15)*32 + laneh*8];
    #pragma unroll
    for (int i = 0; i < 4; i++)
      #pragma unroll
      for (int j = 0; j < 4; j++)
        acc[i][j] = __builtin_amdgcn_mfma_f32_16x16x32_bf16(af[i], bf[j], acc[i][j], 0, 0, 0);
  }

  #pragma unroll
  for (int i = 0; i < 4; i++) {
    int row = m0 + wm*64 + i*16 + laneh*4;
    #pragma unroll
    for (int j = 0; j < 4; j++) {
      int col = n0 + wn*64 + j*16 + lane15;
      #pragma unroll
      for (int r = 0; r < 4; r++) {
        float v = acc[i][j][r];
        int rr = row + r;
        if constexpr (EPI == 0) {
          if (col < 2048) {
            outB[(size_t)rr*ldc + col] = f2bf(v);
          } else {
            int b = rr >> 10, t = rr & (Tq-1);
            int hd = col - 2048, hh = hd >> 6, d = hd & 63;
            vT[(((size_t)b*Hq + hh)*Dq + d)*Tq + t] = f2bf(v);
          }
        } else if constexpr (EPI == 1) {
          float z = v + bias[col];
          float gl = 0.5f * z * (1.f + erff(z * 0.70710678118654752440f));
          outB[(size_t)rr*ldc + col] = f2bf(gl);
        } else {
          outF[(size_t)rr*ldf + col] += v + bias[col];
        }
      }
    }
  }
}

// ---------------- flash attention (causal), 1 block per (b,h, 64-row q tile) ----------------
__global__ __launch_bounds__(256)
void attn_kernel(const unsigned short* __restrict__ qk,   // (BT, 2048): q cols 0..1023, k cols 1024..2047
                 const unsigned short* __restrict__ vT,   // (B,H,D,T)
                 unsigned short* __restrict__ ob)         // (BT, 1024)
{
  __shared__ unsigned short Ks [64*64];
  __shared__ unsigned short Vts[64*64];
  __shared__ unsigned short Ps [4*16*64];
  int tid = threadIdx.x, lane = tid & 63, wv = tid >> 6;
  int lane15 = lane & 15, laneh = lane >> 4;
  int blk = blockIdx.x;
  int qt = blk & 15, bh = blk >> 4;
  int h = bh & (Hq-1), b = bh >> 4;
  int qrow0 = qt*64 + wv*16;
  size_t tokbase = (size_t)b * Tq;

  // Q fragments (A operand: m=lane15, k=laneh*8 + kk*32), held in regs
  bf16x8 qf[2];
  {
    int t = qrow0 + lane15;
    const unsigned short* qp = qk + (tokbase + t)*2048 + h*64 + laneh*8;
    qf[0] = *(const bf16x8*)(qp);
    qf[1] = *(const bf16x8*)(qp + 32);
  }
  floatx4 oacc[4];
  #pragma unroll
  for (int d = 0; d < 4; d++) oacc[d] = (floatx4){0.f,0.f,0.f,0.f};
  float mrow[4], lrow[4];
  #pragma unroll
  for (int r = 0; r < 4; r++) { mrow[r] = -__builtin_inff(); lrow[r] = 0.f; }

  const unsigned short* Kbase = qk + tokbase*2048 + 1024 + h*64;
  const unsigned short* Vbase = vT + (size_t)bh * Dq * Tq;
  int jend = qt*64;

  for (int j0 = 0; j0 <= jend; j0 += 64) {
    __syncthreads();
    // 64x64 bf16 tile = 512 sixteen-byte segments; row = seg>>3, col = (seg&7)*8
    #pragma unroll
    for (int i = 0; i < 2; i++) {
      int seg = (wv*2+i)*64 + lane;
      int row = seg >> 3, col8 = (seg & 7) * 8;
      gld_lds16(Kbase + (size_t)(j0+row)*2048 + col8, &Ks [(wv*2+i)*512]);
      gld_lds16(Vbase + (size_t)row*Tq + j0 + col8,   &Vts[(wv*2+i)*512]);
    }
    __syncthreads();

    // S = Q @ K^T (per wave: 16 q-rows x 64 kv-cols)
    floatx4 sac[4];
    #pragma unroll
    for (int jt = 0; jt < 4; jt++) {
      sac[jt] = (floatx4){0.f,0.f,0.f,0.f};
      bf16x8 kf0 = *(const bf16x8*)&Ks[(jt*16+lane15)*64 + laneh*8];
      bf16x8 kf1 = *(const bf16x8*)&Ks[(jt*16+lane15)*64 + 32 + laneh*8];
      sac[jt] = __builtin_amdgcn_mfma_f32_16x16x32_bf16(qf[0], kf0, sac[jt], 0, 0, 0);
      sac[jt] = __builtin_amdgcn_mfma_f32_16x16x32_bf16(qf[1], kf1, sac[jt], 0, 0, 0);
    }
    // scale + causal mask (C layout: row=laneh*4+r, col=lane15)
    int trow = qrow0 + laneh*4;
    #pragma unroll
    for (int jt = 0; jt < 4; jt++) {
      int col = j0 + jt*16 + lane15;
      #pragma unroll
      for (int r = 0; r < 4; r++) {
        float s = sac[jt][r] * 0.125f;
        sac[jt][r] = (col <= trow + r) ? s : -__builtin_inff();
      }
    }
    // online softmax
    float alpha[4];
    #pragma unroll
    for (int r = 0; r < 4; r++) {
      float mx = fmaxf(fmaxf(sac[0][r], sac[1][r]), fmaxf(sac[2][r], sac[3][r]));
      #pragma unroll
      for (int s = 1; s < 16; s <<= 1) mx = fmaxf(mx, __shfl_xor(mx, s, 64));
      float mn = fmaxf(mrow[r], mx);
      alpha[r] = expf(mrow[r] - mn);
      float psum = 0.f;
      #pragma unroll
      for (int jt = 0; jt < 4; jt++) {
        float p = expf(sac[jt][r] - mn);
        sac[jt][r] = p;
        psum += p;
      }
      #pragma unroll
      for (int s = 1; s < 16; s <<= 1) psum += __shfl_xor(psum, s, 64);
      lrow[r] = lrow[r] * alpha[r] + psum;
      mrow[r] = mn;
    }
    #pragma unroll
    for (int dt = 0; dt < 4; dt++)
      #pragma unroll
      for (int r = 0; r < 4; r++) oacc[dt][r] *= alpha[r];

    // P: C-layout -> A-layout via LDS
    unsigned short* Pw = &Ps[wv*1024];
    #pragma unroll
    for (int jt = 0; jt < 4; jt++)
      #pragma unroll
      for (int r = 0; r < 4; r++)
        Pw[(laneh*4 + r)*64 + jt*16 + lane15] = f2bf(sac[jt][r]);
    __syncthreads();
    bf16x8 pf0 = *(const bf16x8*)&Ps[wv*1024 + lane15*64 + laneh*8];
    bf16x8 pf1 = *(const bf16x8*)&Ps[wv*1024 + lane15*64 + 32 + laneh*8];
    #pragma unroll
    for (int dt = 0; dt < 4; dt++) {
      bf16x8 vf0 = *(const bf16x8*)&Vts[(dt*16+lane15)*64 + laneh*8];
      bf16x8 vf1 = *(const bf16x8*)&Vts[(dt*16+lane15)*64 + 32 + laneh*8];
      oacc[dt] = __builtin_amdgcn_mfma_f32_16x16x32_bf16(pf0, vf0, oacc[dt], 0, 0, 0);
      oacc[dt] = __builtin_amdgcn_mfma_f32_16x16x32_bf16(pf1, vf1, oacc[dt], 0, 0, 0);
    }
  }
  // epilogue: O /= l
  #pragma unroll
  for (int r = 0; r < 4; r++) {
    int t = qrow0 + laneh*4 + r;
    float inv = 1.f / lrow[r];
    unsigned short* orow = ob + (tokbase + t)*Cq + h*64;
    #pragma unroll
    for (int dt = 0; dt < 4; dt++)
      orow[dt*16 + lane15] = f2bf(oacc[dt][r] * inv);
  }
}

// ---------------- head: logits = x@lmW + lmb; log_softmax(0..63) ++ log_sigmoid(64) ----------------
__global__ __launch_bounds__(64) void head_kernel(
    const float* __restrict__ x, const float* __restrict__ lmW,
    const float* __restrict__ lmb, float* __restrict__ out)
{
  __shared__ float xs[Cq];
  int tok = blockIdx.x, lane = threadIdx.x;
  const float* xrow = x + (size_t)tok * Cq;
  #pragma unroll
  for (int i = 0; i < 16; i++) xs[i*64 + lane] = xrow[i*64 + lane];
  __syncthreads();
  float acc  = lmb[lane];
  float acc2 = lmb[64];
  #pragma unroll 4
  for (int c = 0; c < Cq; c++) {
    float xv = xs[c];
    acc  = fmaf(xv, lmW[c*65 + lane], acc);
    acc2 = fmaf(xv, lmW[c*65 + 64],  acc2);
  }
  float m = acc;
  #pragma unroll
  for (int s = 32; s >= 1; s >>= 1) m = fmaxf(m, __shfl_xor(m, s, 64));
  float e = expf(acc - m), se = e;
  #pragma unroll
  for (int s = 32; s >= 1; s >>= 1) se += __shfl_xor(se, s, 64);
  float lse = m + logf(se);
  out[(size_t)tok*65 + lane] = acc - lse;
  if (lane == 0) {
    float z = acc2;
    float ls = (z >= 0.f) ? -log1pf(expf(-z)) : (z - log1pf(expf(z)));
    out[(size_t)tok*65 + 64] = ls;
  }
}

extern "C" void kernel_launch(void* const* d_in, const int* in_sizes, int n_in,
                              void* d_out, int out_size, void* d_ws, size_t ws_size,
                              hipStream_t stream) {
  const int*   acts = (const int*)  d_in[0];
  const float* dur  = (const float*)d_in[1];
  const float* emb  = (const float*)d_in[2];
  const float* pos  = (const float*)d_in[3];
  const float* Wq   = (const float*)d_in[4];
  const float* Wk   = (const float*)d_in[5];
  const float* Wv   = (const float*)d_in[6];
  const float* Wo   = (const float*)d_in[7];
  const float* bo   = (const float*)d_in[8];
  const float* W1   = (const float*)d_in[9];
  const float* b1   = (const float*)d_in[10];
  const float* W2   = (const float*)d_in[11];
  const float* b2   = (const float*)d_in[12];
  const float* g1   = (const float*)d_in[13];
  const float* g2   = (const float*)d_in[14];
  const float* lmW  = (const float*)d_in[15];
  const float* lmb  = (const float*)d_in[16];
  float* out = (float*)d_out;
  (void)in_sizes; (void)n_in; (void)out_size; (void)ws_size;

  char* w = (char*)d_ws;
  auto take = [&](size_t bytes) { char* p = w; w += (bytes + 255) & ~(size_t)255; return p; };
  // union region: [qk | vT | ob] is exactly 33.55 MB == m1 (aliased; lifetimes disjoint)
  unsigned short* qk  = (unsigned short*)take((size_t)BT*2048*2);
  unsigned short* vT  = (unsigned short*)take((size_t)Bq*Hq*Dq*Tq*2);
  unsigned short* ob  = (unsigned short*)take((size_t)BT*Cq*2);
  unsigned short* m1  = qk;
  unsigned short* hb  = (unsigned short*)take((size_t)BT*Cq*2);
  float*          x   = (float*)take((size_t)BT*Cq*4);
  unsigned short* wqkvl = (unsigned short*)take((size_t)3072*Cq*2);
  unsigned short* wol   = (unsigned short*)take((size_t)Cq*Cq*2);
  unsigned short* w1l   = (unsigned short*)take((size_t)Fq*Cq*2);
  unsigned short* w2l   = (unsigned short*)take((size_t)Cq*Fq*2);

  dim3 tb(32, 8);
  embed_kernel<<<BT, 256, 0, stream>>>(acts, dur, emb, pos, x);

  for (int l = 0; l < Lq; l++) {
    // per-layer weight transposes -> bf16 (N,K) layouts
    transpose_cast_kernel<<<dim3(2,32,16), tb, 0, stream>>>(
        Wq + (size_t)l*Hq*Cq*Dq, wqkvl,               1024, 64, 16, 0, (long long)64*1024);
    transpose_cast_kernel<<<dim3(2,32,16), tb, 0, stream>>>(
        Wk + (size_t)l*Hq*Cq*Dq, wqkvl + 1024*1024,   1024, 64, 16, 0, (long long)64*1024);
    transpose_cast_kernel<<<dim3(2,32,16), tb, 0, stream>>>(
        Wv + (size_t)l*Hq*Cq*Dq, wqkvl + 2048*1024,   1024, 64, 16, 0, (long long)64*1024);
    transpose_cast_kernel<<<dim3(32,32,1), tb, 0, stream>>>(
        Wo + (size_t)l*Cq*Cq,    wol,  1024, 1024, 1, 0, 0);
    transpose_cast_kernel<<<dim3(128,32,1), tb, 0, stream>>>(
        W1 + (size_t)l*Cq*Fq,    w1l,  1024, 4096, 1, 0, 0);
    transpose_cast_kernel<<<dim3(32,128,1), tb, 0, stream>>>(
        W2 + (size_t)l*Fq*Cq,    w2l,  4096, 1024, 1, 0, 0);

    rmsnorm_kernel<<<BT, 256, 0, stream>>>(x, g1 + l*Cq, hb);
    gemm_bt_kernel<0><<<dim3(24,32), 256, 0, stream>>>(
        hb, Cq, wqkvl, Cq, Cq, qk, 2048, vT, nullptr, 0, nullptr);
    attn_kernel<<<Bq*Hq*16, 256, 0, stream>>>(qk, vT, ob);
    gemm_bt_kernel<2><<<dim3(8,32), 256, 0, stream>>>(
        ob, Cq, wol, Cq, Cq, nullptr, 0, nullptr, x, Cq, bo + l*Cq);
    rmsnorm_kernel<<<BT, 256, 0, stream>>>(x, g2 + l*Cq, hb);
    gemm_bt_kernel<1><<<dim3(32,32), 256, 0, stream>>>(
        hb, Cq, w1l, Cq, Cq, m1, Fq, nullptr, nullptr, 0, b1 + l*Fq);
    gemm_bt_kernel<2><<<dim3(8,32), 256, 0, stream>>>(
        m1, Fq, w2l, Fq, Fq, nullptr, 0, nullptr, x, Cq, b2 + l*Cq);
  }
  head_kernel<<<BT, 64, 0, stream>>>(x, lmW, lmb, out);
}

// Round 3
// 1718.532 us; speedup vs baseline: 1.0462x; 1.0462x over previous
//
#include <hip/hip_runtime.h>

// Problem constants
#define Bq 4
#define Tq 1024
#define Cq 1024
#define Hq 16
#define Dq 64
#define Fq 4096
#define Lq 4
#define BT (Bq*Tq)

typedef __attribute__((ext_vector_type(8))) __bf16 bf16x8;
typedef __attribute__((ext_vector_type(4))) float  floatx4;

__device__ __forceinline__ unsigned short f2bf(float f) {
  unsigned int u = __builtin_bit_cast(unsigned int, f);
  u = (u + 0x7FFFu + ((u >> 16) & 1u)) >> 16;   // RNE
  return (unsigned short)u;
}

// async global->LDS, 16B per lane; lds ptr must be wave-uniform (HW adds lane*16)
__device__ __forceinline__ void gld_lds16(const void* g, void* lds) {
  __builtin_amdgcn_global_load_lds(
      (const __attribute__((address_space(1))) unsigned int*)g,
      (__attribute__((address_space(3))) unsigned int*)lds, 16, 0, 0);
}

// ---------------- embed: x = concat(emb[acts], dur) + pos ----------------
__global__ __launch_bounds__(256) void embed_kernel(
    const int* __restrict__ acts, const float* __restrict__ dur,
    const float* __restrict__ emb, const float* __restrict__ pos,
    float* __restrict__ x)
{
  int tok = blockIdx.x;
  int t = tok & (Tq-1);
  int a = acts[tok];
  const float* er = emb + (size_t)a * (Cq-1);
  const float* pr = pos + (size_t)t * Cq;
  float* xr = x + (size_t)tok * Cq;
  float dv = dur[tok];
  for (int c = threadIdx.x; c < Cq; c += 256) {
    float v = (c < Cq-1) ? er[c] : dv;
    xr[c] = v + pr[c];
  }
}

// ---------------- rmsnorm -> bf16 ----------------
__global__ __launch_bounds__(256) void rmsnorm_kernel(
    const float* __restrict__ x, const float* __restrict__ g,
    unsigned short* __restrict__ h)
{
  int tok = blockIdx.x, tid = threadIdx.x;
  const float4* xr = (const float4*)(x + (size_t)tok * Cq);
  float4 v = xr[tid];
  float ss = v.x*v.x + v.y*v.y + v.z*v.z + v.w*v.w;
  #pragma unroll
  for (int s = 32; s >= 1; s >>= 1) ss += __shfl_xor(ss, s, 64);
  __shared__ float ws4[4];
  if ((tid & 63) == 0) ws4[tid >> 6] = ss;
  __syncthreads();
  float tot = ws4[0] + ws4[1] + ws4[2] + ws4[3];
  float r = rsqrtf(tot * (1.0f/(float)Cq) + 1.1920928955078125e-07f);
  float4 gv = ((const float4*)g)[tid];
  unsigned short o4[4] = { f2bf(v.x*r*gv.x), f2bf(v.y*r*gv.y),
                           f2bf(v.z*r*gv.z), f2bf(v.w*r*gv.w) };
  *(uint2*)(h + (size_t)tok*Cq + tid*4) = *(const uint2*)o4;
}

// ---------------- transpose + cast: in (z batches of R x Cc) f32 -> out (Cc x R) bf16 ----------------
__global__ void transpose_cast_kernel(
    const float* __restrict__ in, unsigned short* __restrict__ out,
    int R, int Cc, int nb2, long long ostr1, long long ostr2)
{
  __shared__ float tile[32][33];
  int c0 = blockIdx.x * 32, r0 = blockIdx.y * 32;
  int tx = threadIdx.x, ty = threadIdx.y;  // 32 x 8
  int z = blockIdx.z;
  const float* ip = in + (size_t)z * R * Cc;
  #pragma unroll
  for (int i = 0; i < 32; i += 8)
    tile[ty+i][tx] = ip[(size_t)(r0+ty+i)*Cc + c0 + tx];
  __syncthreads();
  unsigned short* op = out + (size_t)(z / nb2) * ostr1 + (size_t)(z % nb2) * ostr2;
  #pragma unroll
  for (int i = 0; i < 32; i += 8)
    op[(size_t)(c0+ty+i)*R + r0 + tx] = f2bf(tile[tx][ty+i]);
}

// ---------------- GEMM: C(M,N) = A(M,K) @ Bt(N,K)^T, bf16 in, fp32 acc ----------------
// EPI 0: qkv scatter (q,k -> qkbuf bf16 ldc=2048; v -> vT[b][h][d][t])
// EPI 1: bf16 store of gelu(acc + bias)
// EPI 2: outF += acc + bias  (fp32 residual add)
template <int EPI>
__global__ __launch_bounds__(256)
void gemm_bt_kernel(const unsigned short* __restrict__ A, int lda,
                    const unsigned short* __restrict__ Bt, int ldb,
                    int K,
                    unsigned short* __restrict__ outB, int ldc,
                    unsigned short* __restrict__ vT,
                    float* __restrict__ outF, int ldf,
                    const float* __restrict__ bias)
{
  __shared__ unsigned short lds_a[128*32];
  __shared__ unsigned short lds_b[128*32];
  int tid = threadIdx.x;
  int lane = tid & 63, wv = tid >> 6;
  int lane15 = lane & 15, laneh = lane >> 4;
  int m0 = blockIdx.y * 128, n0 = blockIdx.x * 128;
  int wm = wv & 1, wn = wv >> 1;

  floatx4 acc[4][4];
  #pragma unroll
  for (int i = 0; i < 4; i++)
    #pragma unroll
    for (int j = 0; j < 4; j++) acc[i][j] = (floatx4){0.f,0.f,0.f,0.f};

  int seg0 = (wv*2+0)*64 + lane;
  int seg1 = (wv*2+1)*64 + lane;
  int ra0 = seg0 >> 2, ca0 = (seg0 & 3) * 8;
  int ra1 = seg1 >> 2, ca1 = (seg1 & 3) * 8;
  const unsigned short* a_src0 = A  + (size_t)(m0+ra0)*lda + ca0;
  const unsigned short* a_src1 = A  + (size_t)(m0+ra1)*lda + ca1;
  const unsigned short* b_src0 = Bt + (size_t)(n0+ra0)*ldb + ca0;
  const unsigned short* b_src1 = Bt + (size_t)(n0+ra1)*ldb + ca1;
  unsigned short* a_dst0 = &lds_a[(wv*2+0)*512];
  unsigned short* a_dst1 = &lds_a[(wv*2+1)*512];
  unsigned short* b_dst0 = &lds_b[(wv*2+0)*512];
  unsigned short* b_dst1 = &lds_b[(wv*2+1)*512];

  for (int k0 = 0; k0 < K; k0 += 32) {
    __syncthreads();
    gld_lds16(a_src0 + k0, a_dst0);
    gld_lds16(a_src1 + k0, a_dst1);
    gld_lds16(b_src0 + k0, b_dst0);
    gld_lds16(b_src1 + k0, b_dst1);
    __syncthreads();
    bf16x8 af[4], bf[4];
    #pragma unroll
    for (int i = 0; i < 4; i++)
      af[i] = *(const bf16x8*)&lds_a[(wm*64 + i*16 + lane15)*32 + laneh*8];
    #pragma unroll
    for (int j = 0; j < 4; j++)
      bf[j] = *(const bf16x8*)&lds_b[(wn*64 + j*16 + lane15)*32 + laneh*8];
    #pragma unroll
    for (int i = 0; i < 4; i++)
      #pragma unroll
      for (int j = 0; j < 4; j++)
        acc[i][j] = __builtin_amdgcn_mfma_f32_16x16x32_bf16(af[i], bf[j], acc[i][j], 0, 0, 0);
  }

  #pragma unroll
  for (int i = 0; i < 4; i++) {
    int row = m0 + wm*64 + i*16 + laneh*4;
    #pragma unroll
    for (int j = 0; j < 4; j++) {
      int col = n0 + wn*64 + j*16 + lane15;
      #pragma unroll
      for (int r = 0; r < 4; r++) {
        float v = acc[i][j][r];
        int rr = row + r;
        if constexpr (EPI == 0) {
          if (col < 2048) {
            outB[(size_t)rr*ldc + col] = f2bf(v);
          } else {
            int b = rr >> 10, t = rr & (Tq-1);
            int hd = col - 2048, hh = hd >> 6, d = hd & 63;
            vT[(((size_t)b*Hq + hh)*Dq + d)*Tq + t] = f2bf(v);
          }
        } else if constexpr (EPI == 1) {
          float z = v + bias[col];
          float gl = 0.5f * z * (1.f + erff(z * 0.70710678118654752440f));
          outB[(size_t)rr*ldc + col] = f2bf(gl);
        } else {
          outF[(size_t)rr*ldf + col] += v + bias[col];
        }
      }
    }
  }
}

// ---------------- flash attention (causal), 1 block per (b,h, 64-row q tile) ----------------
__global__ __launch_bounds__(256)
void attn_kernel(const unsigned short* __restrict__ qk,   // (BT, 2048): q cols 0..1023, k cols 1024..2047
                 const unsigned short* __restrict__ vT,   // (B,H,D,T)
                 unsigned short* __restrict__ ob)         // (BT, 1024)
{
  __shared__ unsigned short Ks [64*64];
  __shared__ unsigned short Vts[64*64];
  __shared__ unsigned short Ps [4*16*64];
  int tid = threadIdx.x, lane = tid & 63, wv = tid >> 6;
  int lane15 = lane & 15, laneh = lane >> 4;
  int blk = blockIdx.x;
  int qt = blk & 15, bh = blk >> 4;
  int h = bh & (Hq-1), b = bh >> 4;
  int qrow0 = qt*64 + wv*16;
  size_t tokbase = (size_t)b * Tq;

  // Q fragments (A operand: m=lane15, k=laneh*8 + kk*32), held in regs
  bf16x8 qf[2];
  {
    int t = qrow0 + lane15;
    const unsigned short* qp = qk + (tokbase + t)*2048 + h*64 + laneh*8;
    qf[0] = *(const bf16x8*)(qp);
    qf[1] = *(const bf16x8*)(qp + 32);
  }
  floatx4 oacc[4];
  #pragma unroll
  for (int d = 0; d < 4; d++) oacc[d] = (floatx4){0.f,0.f,0.f,0.f};
  float mrow[4], lrow[4];
  #pragma unroll
  for (int r = 0; r < 4; r++) { mrow[r] = -__builtin_inff(); lrow[r] = 0.f; }

  const unsigned short* Kbase = qk + tokbase*2048 + 1024 + h*64;
  const unsigned short* Vbase = vT + (size_t)bh * Dq * Tq;
  int jend = qt*64;

  for (int j0 = 0; j0 <= jend; j0 += 64) {
    __syncthreads();
    // 64x64 bf16 tile = 512 sixteen-byte segments; row = seg>>3, col = (seg&7)*8
    #pragma unroll
    for (int i = 0; i < 2; i++) {
      int seg = (wv*2+i)*64 + lane;
      int row = seg >> 3, col8 = (seg & 7) * 8;
      gld_lds16(Kbase + (size_t)(j0+row)*2048 + col8, &Ks [(wv*2+i)*512]);
      gld_lds16(Vbase + (size_t)row*Tq + j0 + col8,   &Vts[(wv*2+i)*512]);
    }
    __syncthreads();

    // S = Q @ K^T (per wave: 16 q-rows x 64 kv-cols)
    floatx4 sac[4];
    #pragma unroll
    for (int jt = 0; jt < 4; jt++) {
      sac[jt] = (floatx4){0.f,0.f,0.f,0.f};
      bf16x8 kf0 = *(const bf16x8*)&Ks[(jt*16+lane15)*64 + laneh*8];
      bf16x8 kf1 = *(const bf16x8*)&Ks[(jt*16+lane15)*64 + 32 + laneh*8];
      sac[jt] = __builtin_amdgcn_mfma_f32_16x16x32_bf16(qf[0], kf0, sac[jt], 0, 0, 0);
      sac[jt] = __builtin_amdgcn_mfma_f32_16x16x32_bf16(qf[1], kf1, sac[jt], 0, 0, 0);
    }
    // scale + causal mask (C layout: row=laneh*4+r, col=lane15)
    int trow = qrow0 + laneh*4;
    #pragma unroll
    for (int jt = 0; jt < 4; jt++) {
      int col = j0 + jt*16 + lane15;
      #pragma unroll
      for (int r = 0; r < 4; r++) {
        float s = sac[jt][r] * 0.125f;
        sac[jt][r] = (col <= trow + r) ? s : -__builtin_inff();
      }
    }
    // online softmax
    float alpha[4];
    #pragma unroll
    for (int r = 0; r < 4; r++) {
      float mx = fmaxf(fmaxf(sac[0][r], sac[1][r]), fmaxf(sac[2][r], sac[3][r]));
      #pragma unroll
      for (int s = 1; s < 16; s <<= 1) mx = fmaxf(mx, __shfl_xor(mx, s, 64));
      float mn = fmaxf(mrow[r], mx);
      alpha[r] = expf(mrow[r] - mn);
      float psum = 0.f;
      #pragma unroll
      for (int jt = 0; jt < 4; jt++) {
        float p = expf(sac[jt][r] - mn);
        sac[jt][r] = p;
        psum += p;
      }
      #pragma unroll
      for (int s = 1; s < 16; s <<= 1) psum += __shfl_xor(psum, s, 64);
      lrow[r] = lrow[r] * alpha[r] + psum;
      mrow[r] = mn;
    }
    #pragma unroll
    for (int dt = 0; dt < 4; dt++)
      #pragma unroll
      for (int r = 0; r < 4; r++) oacc[dt][r] *= alpha[r];

    // P: C-layout -> A-layout via LDS
    unsigned short* Pw = &Ps[wv*1024];
    #pragma unroll
    for (int jt = 0; jt < 4; jt++)
      #pragma unroll
      for (int r = 0; r < 4; r++)
        Pw[(laneh*4 + r)*64 + jt*16 + lane15] = f2bf(sac[jt][r]);
    __syncthreads();
    bf16x8 pf0 = *(const bf16x8*)&Ps[wv*1024 + lane15*64 + laneh*8];
    bf16x8 pf1 = *(const bf16x8*)&Ps[wv*1024 + lane15*64 + 32 + laneh*8];
    #pragma unroll
    for (int dt = 0; dt < 4; dt++) {
      bf16x8 vf0 = *(const bf16x8*)&Vts[(dt*16+lane15)*64 + laneh*8];
      bf16x8 vf1 = *(const bf16x8*)&Vts[(dt*16+lane15)*64 + 32 + laneh*8];
      oacc[dt] = __builtin_amdgcn_mfma_f32_16x16x32_bf16(pf0, vf0, oacc[dt], 0, 0, 0);
      oacc[dt] = __builtin_amdgcn_mfma_f32_16x16x32_bf16(pf1, vf1, oacc[dt], 0, 0, 0);
    }
  }
  // epilogue: O /= l
  #pragma unroll
  for (int r = 0; r < 4; r++) {
    int t = qrow0 + laneh*4 + r;
    float inv = 1.f / lrow[r];
    unsigned short* orow = ob + (tokbase + t)*Cq + h*64;
    #pragma unroll
    for (int dt = 0; dt < 4; dt++)
      orow[dt*16 + lane15] = f2bf(oacc[dt][r] * inv);
  }
}

// ---------------- lm head prep: lmWt (64 x 1024 bf16, B-operand rows) + lmWcol (fp32, col 64) ----------------
__global__ __launch_bounds__(256) void lmw_prep_kernel(
    const float* __restrict__ lmW, unsigned short* __restrict__ lmWt,
    float* __restrict__ lmWcol)
{
  int idx = blockIdx.x * 256 + threadIdx.x;   // 65536 threads
  int n = idx & 63, k = idx >> 6;
  lmWt[(size_t)n*Cq + k] = f2bf(lmW[(size_t)k*65 + n]);
  if (idx < Cq) lmWcol[idx] = lmW[(size_t)idx*65 + 64];
}

// ---------------- head: 1 wave per 16 tokens; MFMA logits + fused log-softmax + log-sigmoid(dur) ----------------
__global__ __launch_bounds__(64) void head_mfma_kernel(
    const float* __restrict__ x, const unsigned short* __restrict__ lmWt,
    const float* __restrict__ lmWcol, const float* __restrict__ lmb,
    float* __restrict__ out)
{
  int lane = threadIdx.x;
  int lane15 = lane & 15, laneh = lane >> 4;
  int tok0 = blockIdx.x * 16;

  floatx4 acc[4];
  #pragma unroll
  for (int jt = 0; jt < 4; jt++) acc[jt] = (floatx4){0.f,0.f,0.f,0.f};

  const float* xrow = x + (size_t)(tok0 + lane15) * Cq + laneh*8;
  const unsigned short* brow = lmWt + (size_t)lane15 * Cq + laneh*8;

  for (int k0 = 0; k0 < Cq; k0 += 32) {
    float4 a0 = *(const float4*)(xrow + k0);
    float4 a1 = *(const float4*)(xrow + k0 + 4);
    bf16x8 af;
    af[0] = (__bf16)a0.x; af[1] = (__bf16)a0.y; af[2] = (__bf16)a0.z; af[3] = (__bf16)a0.w;
    af[4] = (__bf16)a1.x; af[5] = (__bf16)a1.y; af[6] = (__bf16)a1.z; af[7] = (__bf16)a1.w;
    #pragma unroll
    for (int jt = 0; jt < 4; jt++) {
      bf16x8 bfv = *(const bf16x8*)(brow + (size_t)jt*16*Cq + k0);
      acc[jt] = __builtin_amdgcn_mfma_f32_16x16x32_bf16(af, bfv, acc[jt], 0, 0, 0);
    }
  }
  // + bias (per output column)
  #pragma unroll
  for (int jt = 0; jt < 4; jt++) {
    float bias = lmb[jt*16 + lane15];
    #pragma unroll
    for (int r = 0; r < 4; r++) acc[jt][r] += bias;
  }
  // log-softmax per token row (C layout: tok = tok0 + laneh*4 + r, col = jt*16 + lane15)
  #pragma unroll
  for (int r = 0; r < 4; r++) {
    float m = fmaxf(fmaxf(acc[0][r], acc[1][r]), fmaxf(acc[2][r], acc[3][r]));
    #pragma unroll
    for (int s = 1; s < 16; s <<= 1) m = fmaxf(m, __shfl_xor(m, s, 64));
    float se = 0.f;
    #pragma unroll
    for (int jt = 0; jt < 4; jt++) se += expf(acc[jt][r] - m);
    #pragma unroll
    for (int s = 1; s < 16; s <<= 1) se += __shfl_xor(se, s, 64);
    float lse = m + logf(se);
    int tok = tok0 + laneh*4 + r;
    float* orow = out + (size_t)tok * 65;
    #pragma unroll
    for (int jt = 0; jt < 4; jt++)
      orow[jt*16 + lane15] = acc[jt][r] - lse;
  }
  // duration logit: exact fp32 dot, 4 lanes per token
  int t = lane >> 2, kq = (lane & 3) * 256;
  const float* xr2 = x + (size_t)(tok0 + t) * Cq + kq;
  const float* wc = lmWcol + kq;
  float s = 0.f;
  #pragma unroll 4
  for (int i = 0; i < 256; i += 4) {
    float4 xv = *(const float4*)(xr2 + i);
    float4 wv = *(const float4*)(wc + i);
    s += xv.x*wv.x + xv.y*wv.y + xv.z*wv.z + xv.w*wv.w;
  }
  s += __shfl_xor(s, 1, 64);
  s += __shfl_xor(s, 2, 64);
  if ((lane & 3) == 0) {
    float z = s + lmb[64];
    float ls = (z >= 0.f) ? -log1pf(expf(-z)) : (z - log1pf(expf(z)));
    out[(size_t)(tok0 + t) * 65 + 64] = ls;
  }
}

extern "C" void kernel_launch(void* const* d_in, const int* in_sizes, int n_in,
                              void* d_out, int out_size, void* d_ws, size_t ws_size,
                              hipStream_t stream) {
  const int*   acts = (const int*)  d_in[0];
  const float* dur  = (const float*)d_in[1];
  const float* emb  = (const float*)d_in[2];
  const float* pos  = (const float*)d_in[3];
  const float* Wq   = (const float*)d_in[4];
  const float* Wk   = (const float*)d_in[5];
  const float* Wv   = (const float*)d_in[6];
  const float* Wo   = (const float*)d_in[7];
  const float* bo   = (const float*)d_in[8];
  const float* W1   = (const float*)d_in[9];
  const float* b1   = (const float*)d_in[10];
  const float* W2   = (const float*)d_in[11];
  const float* b2   = (const float*)d_in[12];
  const float* g1   = (const float*)d_in[13];
  const float* g2   = (const float*)d_in[14];
  const float* lmW  = (const float*)d_in[15];
  const float* lmb  = (const float*)d_in[16];
  float* out = (float*)d_out;
  (void)in_sizes; (void)n_in; (void)out_size; (void)ws_size;

  char* w = (char*)d_ws;
  auto take = [&](size_t bytes) { char* p = w; w += (bytes + 255) & ~(size_t)255; return p; };
  // union region: [qk | vT | ob] is exactly 33.55 MB == m1 (aliased; lifetimes disjoint)
  unsigned short* qk  = (unsigned short*)take((size_t)BT*2048*2);
  unsigned short* vT  = (unsigned short*)take((size_t)Bq*Hq*Dq*Tq*2);
  unsigned short* ob  = (unsigned short*)take((size_t)BT*Cq*2);
  unsigned short* m1  = qk;
  unsigned short* hb  = (unsigned short*)take((size_t)BT*Cq*2);
  float*          x   = (float*)take((size_t)BT*Cq*4);
  unsigned short* wqkvl = (unsigned short*)take((size_t)3072*Cq*2);
  unsigned short* wol   = (unsigned short*)take((size_t)Cq*Cq*2);
  unsigned short* w1l   = (unsigned short*)take((size_t)Fq*Cq*2);
  unsigned short* w2l   = (unsigned short*)take((size_t)Cq*Fq*2);
  unsigned short* lmWt  = (unsigned short*)take((size_t)64*Cq*2);
  float*          lmWcol= (float*)take((size_t)Cq*4);

  dim3 tb(32, 8);
  embed_kernel<<<BT, 256, 0, stream>>>(acts, dur, emb, pos, x);
  lmw_prep_kernel<<<256, 256, 0, stream>>>(lmW, lmWt, lmWcol);

  for (int l = 0; l < Lq; l++) {
    // per-layer weight transposes -> bf16 (N,K) layouts
    transpose_cast_kernel<<<dim3(2,32,16), tb, 0, stream>>>(
        Wq + (size_t)l*Hq*Cq*Dq, wqkvl,               1024, 64, 16, 0, (long long)64*1024);
    transpose_cast_kernel<<<dim3(2,32,16), tb, 0, stream>>>(
        Wk + (size_t)l*Hq*Cq*Dq, wqkvl + 1024*1024,   1024, 64, 16, 0, (long long)64*1024);
    transpose_cast_kernel<<<dim3(2,32,16), tb, 0, stream>>>(
        Wv + (size_t)l*Hq*Cq*Dq, wqkvl + 2048*1024,   1024, 64, 16, 0, (long long)64*1024);
    transpose_cast_kernel<<<dim3(32,32,1), tb, 0, stream>>>(
        Wo + (size_t)l*Cq*Cq,    wol,  1024, 1024, 1, 0, 0);
    transpose_cast_kernel<<<dim3(128,32,1), tb, 0, stream>>>(
        W1 + (size_t)l*Cq*Fq,    w1l,  1024, 4096, 1, 0, 0);
    transpose_cast_kernel<<<dim3(32,128,1), tb, 0, stream>>>(
        W2 + (size_t)l*Fq*Cq,    w2l,  4096, 1024, 1, 0, 0);

    rmsnorm_kernel<<<BT, 256, 0, stream>>>(x, g1 + l*Cq, hb);
    gemm_bt_kernel<0><<<dim3(24,32), 256, 0, stream>>>(
        hb, Cq, wqkvl, Cq, Cq, qk, 2048, vT, nullptr, 0, nullptr);
    attn_kernel<<<Bq*Hq*16, 256, 0, stream>>>(qk, vT, ob);
    gemm_bt_kernel<2><<<dim3(8,32), 256, 0, stream>>>(
        ob, Cq, wol, Cq, Cq, nullptr, 0, nullptr, x, Cq, bo + l*Cq);
    rmsnorm_kernel<<<BT, 256, 0, stream>>>(x, g2 + l*Cq, hb);
    gemm_bt_kernel<1><<<dim3(32,32), 256, 0, stream>>>(
        hb, Cq, w1l, Cq, Cq, m1, Fq, nullptr, nullptr, 0, b1 + l*Fq);
    gemm_bt_kernel<2><<<dim3(8,32), 256, 0, stream>>>(
        m1, Fq, w2l, Fq, Fq, nullptr, 0, nullptr, x, Cq, b2 + l*Cq);
  }
  head_mfma_kernel<<<BT/16, 64, 0, stream>>>(x, lmWt, lmWcol, lmb, out);
}

// Round 4
// 1604.026 us; speedup vs baseline: 1.1209x; 1.0714x over previous
//
#include <hip/hip_runtime.h>

// Problem constants
#define Bq 4
#define Tq 1024
#define Cq 1024
#define Hq 16
#define Dq 64
#define Fq 4096
#define Lq 4
#define BT (Bq*Tq)

typedef __attribute__((ext_vector_type(8))) __bf16 bf16x8;
typedef __attribute__((ext_vector_type(4))) float  floatx4;

__device__ __forceinline__ unsigned short f2bf(float f) {
  unsigned int u = __builtin_bit_cast(unsigned int, f);
  u = (u + 0x7FFFu + ((u >> 16) & 1u)) >> 16;   // RNE
  return (unsigned short)u;
}

// async global->LDS, 16B per lane; lds ptr must be wave-uniform (HW adds lane*16)
__device__ __forceinline__ void gld_lds16(const void* g, void* lds) {
  __builtin_amdgcn_global_load_lds(
      (const __attribute__((address_space(1))) unsigned int*)g,
      (__attribute__((address_space(3))) unsigned int*)lds, 16, 0, 0);
}

// ---------------- embed: x = concat(emb[acts], dur) + pos ----------------
__global__ __launch_bounds__(256) void embed_kernel(
    const int* __restrict__ acts, const float* __restrict__ dur,
    const float* __restrict__ emb, const float* __restrict__ pos,
    float* __restrict__ x)
{
  int tok = blockIdx.x;
  int t = tok & (Tq-1);
  int a = acts[tok];
  const float* er = emb + (size_t)a * (Cq-1);
  const float* pr = pos + (size_t)t * Cq;
  float* xr = x + (size_t)tok * Cq;
  float dv = dur[tok];
  for (int c = threadIdx.x; c < Cq; c += 256) {
    float v = (c < Cq-1) ? er[c] : dv;
    xr[c] = v + pr[c];
  }
}

// ---------------- rmsnorm -> bf16 ----------------
__global__ __launch_bounds__(256) void rmsnorm_kernel(
    const float* __restrict__ x, const float* __restrict__ g,
    unsigned short* __restrict__ h)
{
  int tok = blockIdx.x, tid = threadIdx.x;
  const float4* xr = (const float4*)(x + (size_t)tok * Cq);
  float4 v = xr[tid];
  float ss = v.x*v.x + v.y*v.y + v.z*v.z + v.w*v.w;
  #pragma unroll
  for (int s = 32; s >= 1; s >>= 1) ss += __shfl_xor(ss, s, 64);
  __shared__ float ws4[4];
  if ((tid & 63) == 0) ws4[tid >> 6] = ss;
  __syncthreads();
  float tot = ws4[0] + ws4[1] + ws4[2] + ws4[3];
  float r = rsqrtf(tot * (1.0f/(float)Cq) + 1.1920928955078125e-07f);
  float4 gv = ((const float4*)g)[tid];
  unsigned short o4[4] = { f2bf(v.x*r*gv.x), f2bf(v.y*r*gv.y),
                           f2bf(v.z*r*gv.z), f2bf(v.w*r*gv.w) };
  *(uint2*)(h + (size_t)tok*Cq + tid*4) = *(const uint2*)o4;
}

// ---------------- transpose + cast: in (z batches of R x Cc) f32 -> out (Cc x R) bf16 ----------------
__global__ void transpose_cast_kernel(
    const float* __restrict__ in, unsigned short* __restrict__ out,
    int R, int Cc, int nb2, long long ostr1, long long ostr2)
{
  __shared__ float tile[32][33];
  int c0 = blockIdx.x * 32, r0 = blockIdx.y * 32;
  int tx = threadIdx.x, ty = threadIdx.y;  // 32 x 8
  int z = blockIdx.z;
  const float* ip = in + (size_t)z * R * Cc;
  #pragma unroll
  for (int i = 0; i < 32; i += 8)
    tile[ty+i][tx] = ip[(size_t)(r0+ty+i)*Cc + c0 + tx];
  __syncthreads();
  unsigned short* op = out + (size_t)(z / nb2) * ostr1 + (size_t)(z % nb2) * ostr2;
  #pragma unroll
  for (int i = 0; i < 32; i += 8)
    op[(size_t)(c0+ty+i)*R + r0 + tx] = f2bf(tile[tx][ty+i]);
}

// ---------------- GEMM: C(M,N) = A(M,K) @ Bt(N,K)^T, bf16 in, fp32 acc ----------------
// LDS layout is XOR-swizzled: 16B segment s holds row=s>>2, data-col8 = (s&3)^(row&3).
// (global_load_lds dest is lane-contiguous, so we permute the SOURCE address per lane.)
// EPI 0: qkv scatter (q,k -> qkbuf bf16 ldc=2048; v -> vT[b][h][d][t])
// EPI 1: bf16 store of gelu(acc + bias)
// EPI 2: outF += acc + bias  (fp32 residual add)
// EPI 3: split-K fp32 partial: outF + blockIdx.z*BT*Cq, k-range [z*KS, z*KS+KS)
template <int EPI>
__global__ __launch_bounds__(256)
void gemm_bt_kernel(const unsigned short* __restrict__ A, int lda,
                    const unsigned short* __restrict__ Bt, int ldb,
                    int KS,
                    unsigned short* __restrict__ outB, int ldc,
                    unsigned short* __restrict__ vT,
                    float* __restrict__ outF, int ldf,
                    const float* __restrict__ bias)
{
  __shared__ unsigned short lds_a[128*32];
  __shared__ unsigned short lds_b[128*32];
  int tid = threadIdx.x;
  int lane = tid & 63, wv = tid >> 6;
  int lane15 = lane & 15, laneh = lane >> 4;
  int m0 = blockIdx.y * 128, n0 = blockIdx.x * 128;
  int wm = wv & 1, wn = wv >> 1;

  floatx4 acc[4][4];
  #pragma unroll
  for (int i = 0; i < 4; i++)
    #pragma unroll
    for (int j = 0; j < 4; j++) acc[i][j] = (floatx4){0.f,0.f,0.f,0.f};

  int seg0 = (wv*2+0)*64 + lane;
  int seg1 = (wv*2+1)*64 + lane;
  // swizzled source column within the 32-wide K-slab
  int ra0 = seg0 >> 2, ca0 = ((seg0 & 3) ^ (ra0 & 3)) * 8;
  int ra1 = seg1 >> 2, ca1 = ((seg1 & 3) ^ (ra1 & 3)) * 8;
  const unsigned short* a_src0 = A  + (size_t)(m0+ra0)*lda + ca0;
  const unsigned short* a_src1 = A  + (size_t)(m0+ra1)*lda + ca1;
  const unsigned short* b_src0 = Bt + (size_t)(n0+ra0)*ldb + ca0;
  const unsigned short* b_src1 = Bt + (size_t)(n0+ra1)*ldb + ca1;
  unsigned short* a_dst0 = &lds_a[(wv*2+0)*512];
  unsigned short* a_dst1 = &lds_a[(wv*2+1)*512];
  unsigned short* b_dst0 = &lds_b[(wv*2+0)*512];
  unsigned short* b_dst1 = &lds_b[(wv*2+1)*512];

  // swizzled read offset: row&3 == lane15&3 for all fragment rows
  int sx = (laneh ^ (lane15 & 3)) * 8;

  int kbeg = (EPI == 3) ? blockIdx.z * KS : 0;
  int kend = kbeg + KS;
  for (int k0 = kbeg; k0 < kend; k0 += 32) {
    __syncthreads();
    gld_lds16(a_src0 + k0, a_dst0);
    gld_lds16(a_src1 + k0, a_dst1);
    gld_lds16(b_src0 + k0, b_dst0);
    gld_lds16(b_src1 + k0, b_dst1);
    __syncthreads();
    bf16x8 af[4], bf[4];
    #pragma unroll
    for (int i = 0; i < 4; i++)
      af[i] = *(const bf16x8*)&lds_a[(wm*64 + i*16 + lane15)*32 + sx];
    #pragma unroll
    for (int j = 0; j < 4; j++)
      bf[j] = *(const bf16x8*)&lds_b[(wn*64 + j*16 + lane15)*32 + sx];
    #pragma unroll
    for (int i = 0; i < 4; i++)
      #pragma unroll
      for (int j = 0; j < 4; j++)
        acc[i][j] = __builtin_amdgcn_mfma_f32_16x16x32_bf16(af[i], bf[j], acc[i][j], 0, 0, 0);
  }

  float* outFz = (EPI == 3) ? outF + (size_t)blockIdx.z * BT * Cq : outF;

  #pragma unroll
  for (int i = 0; i < 4; i++) {
    int row = m0 + wm*64 + i*16 + laneh*4;
    #pragma unroll
    for (int j = 0; j < 4; j++) {
      int col = n0 + wn*64 + j*16 + lane15;
      #pragma unroll
      for (int r = 0; r < 4; r++) {
        float v = acc[i][j][r];
        int rr = row + r;
        if constexpr (EPI == 0) {
          if (col < 2048) {
            outB[(size_t)rr*ldc + col] = f2bf(v);
          } else {
            int b = rr >> 10, t = rr & (Tq-1);
            int hd = col - 2048, hh = hd >> 6, d = hd & 63;
            vT[(((size_t)b*Hq + hh)*Dq + d)*Tq + t] = f2bf(v);
          }
        } else if constexpr (EPI == 1) {
          float z = v + bias[col];
          float gl = 0.5f * z * (1.f + erff(z * 0.70710678118654752440f));
          outB[(size_t)rr*ldc + col] = f2bf(gl);
        } else if constexpr (EPI == 2) {
          outF[(size_t)rr*ldf + col] += v + bias[col];
        } else {
          outFz[(size_t)rr*ldf + col] = v;
        }
      }
    }
  }
}

// ---------------- split-K reduce: x += p0 + p1 + bias ----------------
__global__ __launch_bounds__(256) void splitk_reduce_kernel(
    const float* __restrict__ p, float* __restrict__ x,
    const float* __restrict__ bias)
{
  size_t o = ((size_t)blockIdx.x * 256 + threadIdx.x) * 4;
  float4 a = *(const float4*)(p + o);
  float4 b = *(const float4*)(p + (size_t)BT*Cq + o);
  float4 xv = *(const float4*)(x + o);
  float4 bi = *(const float4*)(bias + (o & (Cq-1)));
  xv.x += a.x + b.x + bi.x;
  xv.y += a.y + b.y + bi.y;
  xv.z += a.z + b.z + bi.z;
  xv.w += a.w + b.w + bi.w;
  *(float4*)(x + o) = xv;
}

// ---------------- flash attention (causal), 1 block per (b,h, 64-row q tile) ----------------
__global__ __launch_bounds__(256)
void attn_kernel(const unsigned short* __restrict__ qk,   // (BT, 2048): q cols 0..1023, k cols 1024..2047
                 const unsigned short* __restrict__ vT,   // (B,H,D,T)
                 unsigned short* __restrict__ ob)         // (BT, 1024)
{
  __shared__ unsigned short Ks [64*64];
  __shared__ unsigned short Vts[64*64];
  __shared__ unsigned short Ps [4*16*64];
  int tid = threadIdx.x, lane = tid & 63, wv = tid >> 6;
  int lane15 = lane & 15, laneh = lane >> 4;
  int blk = blockIdx.x;
  int qt = blk & 15, bh = blk >> 4;
  int h = bh & (Hq-1), b = bh >> 4;
  int qrow0 = qt*64 + wv*16;
  size_t tokbase = (size_t)b * Tq;

  // Q fragments (A operand: m=lane15, k=laneh*8 + kk*32), held in regs
  bf16x8 qf[2];
  {
    int t = qrow0 + lane15;
    const unsigned short* qp = qk + (tokbase + t)*2048 + h*64 + laneh*8;
    qf[0] = *(const bf16x8*)(qp);
    qf[1] = *(const bf16x8*)(qp + 32);
  }
  floatx4 oacc[4];
  #pragma unroll
  for (int d = 0; d < 4; d++) oacc[d] = (floatx4){0.f,0.f,0.f,0.f};
  float mrow[4], lrow[4];
  #pragma unroll
  for (int r = 0; r < 4; r++) { mrow[r] = -__builtin_inff(); lrow[r] = 0.f; }

  const unsigned short* Kbase = qk + tokbase*2048 + 1024 + h*64;
  const unsigned short* Vbase = vT + (size_t)bh * Dq * Tq;
  int jend = qt*64;

  for (int j0 = 0; j0 <= jend; j0 += 64) {
    __syncthreads();
    // 64x64 bf16 tile = 512 sixteen-byte segments; row = seg>>3, col = (seg&7)*8
    #pragma unroll
    for (int i = 0; i < 2; i++) {
      int seg = (wv*2+i)*64 + lane;
      int row = seg >> 3, col8 = (seg & 7) * 8;
      gld_lds16(Kbase + (size_t)(j0+row)*2048 + col8, &Ks [(wv*2+i)*512]);
      gld_lds16(Vbase + (size_t)row*Tq + j0 + col8,   &Vts[(wv*2+i)*512]);
    }
    __syncthreads();

    // S = Q @ K^T (per wave: 16 q-rows x 64 kv-cols)
    floatx4 sac[4];
    #pragma unroll
    for (int jt = 0; jt < 4; jt++) {
      sac[jt] = (floatx4){0.f,0.f,0.f,0.f};
      bf16x8 kf0 = *(const bf16x8*)&Ks[(jt*16+lane15)*64 + laneh*8];
      bf16x8 kf1 = *(const bf16x8*)&Ks[(jt*16+lane15)*64 + 32 + laneh*8];
      sac[jt] = __builtin_amdgcn_mfma_f32_16x16x32_bf16(qf[0], kf0, sac[jt], 0, 0, 0);
      sac[jt] = __builtin_amdgcn_mfma_f32_16x16x32_bf16(qf[1], kf1, sac[jt], 0, 0, 0);
    }
    // scale + causal mask (C layout: row=laneh*4+r, col=lane15)
    int trow = qrow0 + laneh*4;
    #pragma unroll
    for (int jt = 0; jt < 4; jt++) {
      int col = j0 + jt*16 + lane15;
      #pragma unroll
      for (int r = 0; r < 4; r++) {
        float s = sac[jt][r] * 0.125f;
        sac[jt][r] = (col <= trow + r) ? s : -__builtin_inff();
      }
    }
    // online softmax
    float alpha[4];
    #pragma unroll
    for (int r = 0; r < 4; r++) {
      float mx = fmaxf(fmaxf(sac[0][r], sac[1][r]), fmaxf(sac[2][r], sac[3][r]));
      #pragma unroll
      for (int s = 1; s < 16; s <<= 1) mx = fmaxf(mx, __shfl_xor(mx, s, 64));
      float mn = fmaxf(mrow[r], mx);
      alpha[r] = expf(mrow[r] - mn);
      float psum = 0.f;
      #pragma unroll
      for (int jt = 0; jt < 4; jt++) {
        float p = expf(sac[jt][r] - mn);
        sac[jt][r] = p;
        psum += p;
      }
      #pragma unroll
      for (int s = 1; s < 16; s <<= 1) psum += __shfl_xor(psum, s, 64);
      lrow[r] = lrow[r] * alpha[r] + psum;
      mrow[r] = mn;
    }
    #pragma unroll
    for (int dt = 0; dt < 4; dt++)
      #pragma unroll
      for (int r = 0; r < 4; r++) oacc[dt][r] *= alpha[r];

    // P: C-layout -> A-layout via LDS
    unsigned short* Pw = &Ps[wv*1024];
    #pragma unroll
    for (int jt = 0; jt < 4; jt++)
      #pragma unroll
      for (int r = 0; r < 4; r++)
        Pw[(laneh*4 + r)*64 + jt*16 + lane15] = f2bf(sac[jt][r]);
    __syncthreads();
    bf16x8 pf0 = *(const bf16x8*)&Ps[wv*1024 + lane15*64 + laneh*8];
    bf16x8 pf1 = *(const bf16x8*)&Ps[wv*1024 + lane15*64 + 32 + laneh*8];
    #pragma unroll
    for (int dt = 0; dt < 4; dt++) {
      bf16x8 vf0 = *(const bf16x8*)&Vts[(dt*16+lane15)*64 + laneh*8];
      bf16x8 vf1 = *(const bf16x8*)&Vts[(dt*16+lane15)*64 + 32 + laneh*8];
      oacc[dt] = __builtin_amdgcn_mfma_f32_16x16x32_bf16(pf0, vf0, oacc[dt], 0, 0, 0);
      oacc[dt] = __builtin_amdgcn_mfma_f32_16x16x32_bf16(pf1, vf1, oacc[dt], 0, 0, 0);
    }
  }
  // epilogue: O /= l
  #pragma unroll
  for (int r = 0; r < 4; r++) {
    int t = qrow0 + laneh*4 + r;
    float inv = 1.f / lrow[r];
    unsigned short* orow = ob + (tokbase + t)*Cq + h*64;
    #pragma unroll
    for (int dt = 0; dt < 4; dt++)
      orow[dt*16 + lane15] = f2bf(oacc[dt][r] * inv);
  }
}

// ---------------- lm head prep: lmWt (64 x 1024 bf16, B-operand rows) + lmWcol (fp32, col 64) ----------------
__global__ __launch_bounds__(256) void lmw_prep_kernel(
    const float* __restrict__ lmW, unsigned short* __restrict__ lmWt,
    float* __restrict__ lmWcol)
{
  int idx = blockIdx.x * 256 + threadIdx.x;   // 65536 threads
  int n = idx & 63, k = idx >> 6;
  lmWt[(size_t)n*Cq + k] = f2bf(lmW[(size_t)k*65 + n]);
  if (idx < Cq) lmWcol[idx] = lmW[(size_t)idx*65 + 64];
}

// ---------------- head: 1 wave per 16 tokens; MFMA logits + fused log-softmax + log-sigmoid(dur) ----------------
__global__ __launch_bounds__(64) void head_mfma_kernel(
    const float* __restrict__ x, const unsigned short* __restrict__ lmWt,
    const float* __restrict__ lmWcol, const float* __restrict__ lmb,
    float* __restrict__ out)
{
  int lane = threadIdx.x;
  int lane15 = lane & 15, laneh = lane >> 4;
  int tok0 = blockIdx.x * 16;

  floatx4 acc[4];
  #pragma unroll
  for (int jt = 0; jt < 4; jt++) acc[jt] = (floatx4){0.f,0.f,0.f,0.f};

  const float* xrow = x + (size_t)(tok0 + lane15) * Cq + laneh*8;
  const unsigned short* brow = lmWt + (size_t)lane15 * Cq + laneh*8;

  for (int k0 = 0; k0 < Cq; k0 += 32) {
    float4 a0 = *(const float4*)(xrow + k0);
    float4 a1 = *(const float4*)(xrow + k0 + 4);
    bf16x8 af;
    af[0] = (__bf16)a0.x; af[1] = (__bf16)a0.y; af[2] = (__bf16)a0.z; af[3] = (__bf16)a0.w;
    af[4] = (__bf16)a1.x; af[5] = (__bf16)a1.y; af[6] = (__bf16)a1.z; af[7] = (__bf16)a1.w;
    #pragma unroll
    for (int jt = 0; jt < 4; jt++) {
      bf16x8 bfv = *(const bf16x8*)(brow + (size_t)jt*16*Cq + k0);
      acc[jt] = __builtin_amdgcn_mfma_f32_16x16x32_bf16(af, bfv, acc[jt], 0, 0, 0);
    }
  }
  // + bias (per output column)
  #pragma unroll
  for (int jt = 0; jt < 4; jt++) {
    float bias = lmb[jt*16 + lane15];
    #pragma unroll
    for (int r = 0; r < 4; r++) acc[jt][r] += bias;
  }
  // log-softmax per token row (C layout: tok = tok0 + laneh*4 + r, col = jt*16 + lane15)
  #pragma unroll
  for (int r = 0; r < 4; r++) {
    float m = fmaxf(fmaxf(acc[0][r], acc[1][r]), fmaxf(acc[2][r], acc[3][r]));
    #pragma unroll
    for (int s = 1; s < 16; s <<= 1) m = fmaxf(m, __shfl_xor(m, s, 64));
    float se = 0.f;
    #pragma unroll
    for (int jt = 0; jt < 4; jt++) se += expf(acc[jt][r] - m);
    #pragma unroll
    for (int s = 1; s < 16; s <<= 1) se += __shfl_xor(se, s, 64);
    float lse = m + logf(se);
    int tok = tok0 + laneh*4 + r;
    float* orow = out + (size_t)tok * 65;
    #pragma unroll
    for (int jt = 0; jt < 4; jt++)
      orow[jt*16 + lane15] = acc[jt][r] - lse;
  }
  // duration logit: exact fp32 dot, 4 lanes per token
  int t = lane >> 2, kq = (lane & 3) * 256;
  const float* xr2 = x + (size_t)(tok0 + t) * Cq + kq;
  const float* wc = lmWcol + kq;
  float s = 0.f;
  #pragma unroll 4
  for (int i = 0; i < 256; i += 4) {
    float4 xv = *(const float4*)(xr2 + i);
    float4 wv = *(const float4*)(wc + i);
    s += xv.x*wv.x + xv.y*wv.y + xv.z*wv.z + xv.w*wv.w;
  }
  s += __shfl_xor(s, 1, 64);
  s += __shfl_xor(s, 2, 64);
  if ((lane & 3) == 0) {
    float z = s + lmb[64];
    float ls = (z >= 0.f) ? -log1pf(expf(-z)) : (z - log1pf(expf(z)));
    out[(size_t)(tok0 + t) * 65 + 64] = ls;
  }
}

extern "C" void kernel_launch(void* const* d_in, const int* in_sizes, int n_in,
                              void* d_out, int out_size, void* d_ws, size_t ws_size,
                              hipStream_t stream) {
  const int*   acts = (const int*)  d_in[0];
  const float* dur  = (const float*)d_in[1];
  const float* emb  = (const float*)d_in[2];
  const float* pos  = (const float*)d_in[3];
  const float* Wq   = (const float*)d_in[4];
  const float* Wk   = (const float*)d_in[5];
  const float* Wv   = (const float*)d_in[6];
  const float* Wo   = (const float*)d_in[7];
  const float* bo   = (const float*)d_in[8];
  const float* W1   = (const float*)d_in[9];
  const float* b1   = (const float*)d_in[10];
  const float* W2   = (const float*)d_in[11];
  const float* b2   = (const float*)d_in[12];
  const float* g1   = (const float*)d_in[13];
  const float* g2   = (const float*)d_in[14];
  const float* lmW  = (const float*)d_in[15];
  const float* lmb  = (const float*)d_in[16];
  float* out = (float*)d_out;
  (void)in_sizes; (void)n_in; (void)out_size; (void)ws_size;

  char* w = (char*)d_ws;
  auto take = [&](size_t bytes) { char* p = w; w += (bytes + 255) & ~(size_t)255; return p; };
  // union region: [qk | vT | ob] is exactly 33.55 MB == m1 (aliased; lifetimes disjoint)
  unsigned short* qk  = (unsigned short*)take((size_t)BT*2048*2);
  unsigned short* vT  = (unsigned short*)take((size_t)Bq*Hq*Dq*Tq*2);
  unsigned short* ob  = (unsigned short*)take((size_t)BT*Cq*2);
  unsigned short* m1  = qk;
  unsigned short* hb  = (unsigned short*)take((size_t)BT*Cq*2);
  float*          x   = (float*)take((size_t)BT*Cq*4);
  unsigned short* wqkvl = (unsigned short*)take((size_t)3072*Cq*2);
  unsigned short* wol   = (unsigned short*)take((size_t)Cq*Cq*2);
  unsigned short* w1l   = (unsigned short*)take((size_t)Fq*Cq*2);
  unsigned short* w2l   = (unsigned short*)take((size_t)Cq*Fq*2);
  unsigned short* lmWt  = (unsigned short*)take((size_t)64*Cq*2);
  float*          lmWcol= (float*)take((size_t)Cq*4);
  float*          part  = (float*)take((size_t)2*BT*Cq*4);   // split-K partials (32 MB)

  dim3 tb(32, 8);
  embed_kernel<<<BT, 256, 0, stream>>>(acts, dur, emb, pos, x);
  lmw_prep_kernel<<<256, 256, 0, stream>>>(lmW, lmWt, lmWcol);

  for (int l = 0; l < Lq; l++) {
    // per-layer weight transposes -> bf16 (N,K) layouts
    transpose_cast_kernel<<<dim3(2,32,16), tb, 0, stream>>>(
        Wq + (size_t)l*Hq*Cq*Dq, wqkvl,               1024, 64, 16, 0, (long long)64*1024);
    transpose_cast_kernel<<<dim3(2,32,16), tb, 0, stream>>>(
        Wk + (size_t)l*Hq*Cq*Dq, wqkvl + 1024*1024,   1024, 64, 16, 0, (long long)64*1024);
    transpose_cast_kernel<<<dim3(2,32,16), tb, 0, stream>>>(
        Wv + (size_t)l*Hq*Cq*Dq, wqkvl + 2048*1024,   1024, 64, 16, 0, (long long)64*1024);
    transpose_cast_kernel<<<dim3(32,32,1), tb, 0, stream>>>(
        Wo + (size_t)l*Cq*Cq,    wol,  1024, 1024, 1, 0, 0);
    transpose_cast_kernel<<<dim3(128,32,1), tb, 0, stream>>>(
        W1 + (size_t)l*Cq*Fq,    w1l,  1024, 4096, 1, 0, 0);
    transpose_cast_kernel<<<dim3(32,128,1), tb, 0, stream>>>(
        W2 + (size_t)l*Fq*Cq,    w2l,  4096, 1024, 1, 0, 0);

    rmsnorm_kernel<<<BT, 256, 0, stream>>>(x, g1 + l*Cq, hb);
    gemm_bt_kernel<0><<<dim3(24,32), 256, 0, stream>>>(
        hb, Cq, wqkvl, Cq, Cq, qk, 2048, vT, nullptr, 0, nullptr);
    attn_kernel<<<Bq*Hq*16, 256, 0, stream>>>(qk, vT, ob);
    gemm_bt_kernel<2><<<dim3(8,32), 256, 0, stream>>>(
        ob, Cq, wol, Cq, Cq, nullptr, 0, nullptr, x, Cq, bo + l*Cq);
    rmsnorm_kernel<<<BT, 256, 0, stream>>>(x, g2 + l*Cq, hb);
    gemm_bt_kernel<1><<<dim3(32,32), 256, 0, stream>>>(
        hb, Cq, w1l, Cq, Cq, m1, Fq, nullptr, nullptr, 0, b1 + l*Fq);
    // FFN2 split-K=2: fp32 partials then fused reduce (+bias, +residual)
    gemm_bt_kernel<3><<<dim3(8,32,2), 256, 0, stream>>>(
        m1, Fq, w2l, Fq, 2048, nullptr, 0, nullptr, part, Cq, nullptr);
    splitk_reduce_kernel<<<BT*Cq/1024, 256, 0, stream>>>(part, x, b2 + l*Cq);
  }
  head_mfma_kernel<<<BT/16, 64, 0, stream>>>(x, lmWt, lmWcol, lmb, out);
}

// Round 5
// 1508.255 us; speedup vs baseline: 1.1921x; 1.0635x over previous
//
#include <hip/hip_runtime.h>

// Problem constants
#define Bq 4
#define Tq 1024
#define Cq 1024
#define Hq 16
#define Dq 64
#define Fq 4096
#define Lq 4
#define BT (Bq*Tq)

typedef __attribute__((ext_vector_type(8))) __bf16 bf16x8;
typedef __attribute__((ext_vector_type(4))) float  floatx4;

__device__ __forceinline__ unsigned short f2bf(float f) {
  unsigned int u = __builtin_bit_cast(unsigned int, f);
  u = (u + 0x7FFFu + ((u >> 16) & 1u)) >> 16;   // RNE
  return (unsigned short)u;
}

// async global->LDS, 16B per lane; lds ptr must be wave-uniform (HW adds lane*16)
__device__ __forceinline__ void gld_lds16(const void* g, void* lds) {
  __builtin_amdgcn_global_load_lds(
      (const __attribute__((address_space(1))) unsigned int*)g,
      (__attribute__((address_space(3))) unsigned int*)lds, 16, 0, 0);
}

// ---------------- embed: x = concat(emb[acts], dur) + pos ----------------
__global__ __launch_bounds__(256) void embed_kernel(
    const int* __restrict__ acts, const float* __restrict__ dur,
    const float* __restrict__ emb, const float* __restrict__ pos,
    float* __restrict__ x)
{
  int tok = blockIdx.x;
  int t = tok & (Tq-1);
  int a = acts[tok];
  const float* er = emb + (size_t)a * (Cq-1);
  const float* pr = pos + (size_t)t * Cq;
  float* xr = x + (size_t)tok * Cq;
  float dv = dur[tok];
  for (int c = threadIdx.x; c < Cq; c += 256) {
    float v = (c < Cq-1) ? er[c] : dv;
    xr[c] = v + pr[c];
  }
}

// ---------------- rmsnorm -> bf16 ----------------
__global__ __launch_bounds__(256) void rmsnorm_kernel(
    const float* __restrict__ x, const float* __restrict__ g,
    unsigned short* __restrict__ h)
{
  int tok = blockIdx.x, tid = threadIdx.x;
  const float4* xr = (const float4*)(x + (size_t)tok * Cq);
  float4 v = xr[tid];
  float ss = v.x*v.x + v.y*v.y + v.z*v.z + v.w*v.w;
  #pragma unroll
  for (int s = 32; s >= 1; s >>= 1) ss += __shfl_xor(ss, s, 64);
  __shared__ float ws4[4];
  if ((tid & 63) == 0) ws4[tid >> 6] = ss;
  __syncthreads();
  float tot = ws4[0] + ws4[1] + ws4[2] + ws4[3];
  float r = rsqrtf(tot * (1.0f/(float)Cq) + 1.1920928955078125e-07f);
  float4 gv = ((const float4*)g)[tid];
  unsigned short o4[4] = { f2bf(v.x*r*gv.x), f2bf(v.y*r*gv.y),
                           f2bf(v.z*r*gv.z), f2bf(v.w*r*gv.w) };
  *(uint2*)(h + (size_t)tok*Cq + tid*4) = *(const uint2*)o4;
}

// ---------------- transpose + cast: in (z batches of R x Cc) f32 -> out (Cc x R) bf16 ----------------
__global__ void transpose_cast_kernel(
    const float* __restrict__ in, unsigned short* __restrict__ out,
    int R, int Cc, int nb2, long long ostr1, long long ostr2)
{
  __shared__ float tile[32][33];
  int c0 = blockIdx.x * 32, r0 = blockIdx.y * 32;
  int tx = threadIdx.x, ty = threadIdx.y;  // 32 x 8
  int z = blockIdx.z;
  const float* ip = in + (size_t)z * R * Cc;
  #pragma unroll
  for (int i = 0; i < 32; i += 8)
    tile[ty+i][tx] = ip[(size_t)(r0+ty+i)*Cc + c0 + tx];
  __syncthreads();
  unsigned short* op = out + (size_t)(z / nb2) * ostr1 + (size_t)(z % nb2) * ostr2;
  #pragma unroll
  for (int i = 0; i < 32; i += 8)
    op[(size_t)(c0+ty+i)*R + r0 + tx] = f2bf(tile[tx][ty+i]);
}

// ---------------- GEMM: C(M,N) = A(M,K) @ Bt(N,K)^T, bf16 in, fp32 acc ----------------
// Single-barrier double-buffered K-loop: prefetch slab k+1 into buf^1 before
// computing slab k; next iteration's __syncthreads (vmcnt+lgkm drain) lands
// after a full compute phase -> latency overlapped. LDS 2x(8+8) KB.
// EPI 0: qkv scatter (q,k -> qkbuf bf16 ldc=2048; v -> vT[b][h][d][t])
// EPI 1: bf16 store of gelu(acc + bias)   (tanh-form GELU)
// EPI 2: outF += acc + bias  (fp32 residual add)
// EPI 3: split-K fp32 partial: outF + blockIdx.z*BT*Cq, k-range [z*KS, z*KS+KS)
template <int EPI>
__global__ __launch_bounds__(256)
void gemm_bt_kernel(const unsigned short* __restrict__ A, int lda,
                    const unsigned short* __restrict__ Bt, int ldb,
                    int KS,
                    unsigned short* __restrict__ outB, int ldc,
                    unsigned short* __restrict__ vT,
                    float* __restrict__ outF, int ldf,
                    const float* __restrict__ bias)
{
  __shared__ unsigned short lds_a[2*128*32];
  __shared__ unsigned short lds_b[2*128*32];
  int tid = threadIdx.x;
  int lane = tid & 63, wv = tid >> 6;
  int lane15 = lane & 15, laneh = lane >> 4;
  int m0 = blockIdx.y * 128, n0 = blockIdx.x * 128;
  int wm = wv & 1, wn = wv >> 1;

  floatx4 acc[4][4];
  #pragma unroll
  for (int i = 0; i < 4; i++)
    #pragma unroll
    for (int j = 0; j < 4; j++) acc[i][j] = (floatx4){0.f,0.f,0.f,0.f};

  int seg0 = (wv*2+0)*64 + lane;
  int seg1 = (wv*2+1)*64 + lane;
  // swizzled source column within the 32-wide K-slab (reads use matching sx)
  int ra0 = seg0 >> 2, ca0 = ((seg0 & 3) ^ (ra0 & 3)) * 8;
  int ra1 = seg1 >> 2, ca1 = ((seg1 & 3) ^ (ra1 & 3)) * 8;
  const unsigned short* a_src0 = A  + (size_t)(m0+ra0)*lda + ca0;
  const unsigned short* a_src1 = A  + (size_t)(m0+ra1)*lda + ca1;
  const unsigned short* b_src0 = Bt + (size_t)(n0+ra0)*ldb + ca0;
  const unsigned short* b_src1 = Bt + (size_t)(n0+ra1)*ldb + ca1;
  unsigned short* a_dst0 = &lds_a[(wv*2+0)*512];
  unsigned short* a_dst1 = &lds_a[(wv*2+1)*512];
  unsigned short* b_dst0 = &lds_b[(wv*2+0)*512];
  unsigned short* b_dst1 = &lds_b[(wv*2+1)*512];

  // swizzled read offset: row&3 == lane15&3 for all fragment rows
  int sx = (laneh ^ (lane15 & 3)) * 8;

  int kbeg = (EPI == 3) ? blockIdx.z * KS : 0;
  int nIter = KS >> 5;

  auto stage = [&](int k0, int buf) {
    int off = buf * 4096;
    gld_lds16(a_src0 + k0, a_dst0 + off);
    gld_lds16(a_src1 + k0, a_dst1 + off);
    gld_lds16(b_src0 + k0, b_dst0 + off);
    gld_lds16(b_src1 + k0, b_dst1 + off);
  };

  stage(kbeg, 0);
  int cur = 0;
  for (int it = 0; it < nIter; ++it) {
    __syncthreads();                       // drains prefetch (had a full compute phase) + prior LDS reads
    if (it + 1 < nIter) stage(kbeg + (it+1)*32, cur ^ 1);
    const unsigned short* la = &lds_a[cur*4096];
    const unsigned short* lb = &lds_b[cur*4096];
    bf16x8 af[4], bf[4];
    #pragma unroll
    for (int i = 0; i < 4; i++)
      af[i] = *(const bf16x8*)&la[(wm*64 + i*16 + lane15)*32 + sx];
    #pragma unroll
    for (int j = 0; j < 4; j++)
      bf[j] = *(const bf16x8*)&lb[(wn*64 + j*16 + lane15)*32 + sx];
    #pragma unroll
    for (int i = 0; i < 4; i++)
      #pragma unroll
      for (int j = 0; j < 4; j++)
        acc[i][j] = __builtin_amdgcn_mfma_f32_16x16x32_bf16(af[i], bf[j], acc[i][j], 0, 0, 0);
    cur ^= 1;
  }

  float* outFz = (EPI == 3) ? outF + (size_t)blockIdx.z * BT * Cq : outF;

  #pragma unroll
  for (int i = 0; i < 4; i++) {
    int row = m0 + wm*64 + i*16 + laneh*4;
    #pragma unroll
    for (int j = 0; j < 4; j++) {
      int col = n0 + wn*64 + j*16 + lane15;
      #pragma unroll
      for (int r = 0; r < 4; r++) {
        float v = acc[i][j][r];
        int rr = row + r;
        if constexpr (EPI == 0) {
          if (col < 2048) {
            outB[(size_t)rr*ldc + col] = f2bf(v);
          } else {
            int b = rr >> 10, t = rr & (Tq-1);
            int hd = col - 2048, hh = hd >> 6, d = hd & 63;
            vT[(((size_t)b*Hq + hh)*Dq + d)*Tq + t] = f2bf(v);
          }
        } else if constexpr (EPI == 1) {
          float z = v + bias[col];
          // tanh-form GELU (|dev from erf-form| <= ~3e-3, << bf16 rounding)
          float u = 0.79788456080286536f * (z + 0.044715f * z*z*z);
          float t = 1.f - 2.f / (__expf(2.f*u) + 1.f);
          float gl = 0.5f * z * (1.f + t);
          outB[(size_t)rr*ldc + col] = f2bf(gl);
        } else if constexpr (EPI == 2) {
          outF[(size_t)rr*ldf + col] += v + bias[col];
        } else {
          outFz[(size_t)rr*ldf + col] = v;
        }
      }
    }
  }
}

// ---------------- split-K reduce: x += p0 + p1 + bias ----------------
__global__ __launch_bounds__(256) void splitk_reduce_kernel(
    const float* __restrict__ p, float* __restrict__ x,
    const float* __restrict__ bias)
{
  size_t o = ((size_t)blockIdx.x * 256 + threadIdx.x) * 4;
  float4 a = *(const float4*)(p + o);
  float4 b = *(const float4*)(p + (size_t)BT*Cq + o);
  float4 xv = *(const float4*)(x + o);
  float4 bi = *(const float4*)(bias + (o & (Cq-1)));
  xv.x += a.x + b.x + bi.x;
  xv.y += a.y + b.y + bi.y;
  xv.z += a.z + b.z + bi.z;
  xv.w += a.w + b.w + bi.w;
  *(float4*)(x + o) = xv;
}

// ---------------- flash attention (causal), 1 block per (b,h, 64-row q tile) ----------------
__global__ __launch_bounds__(256)
void attn_kernel(const unsigned short* __restrict__ qk,   // (BT, 2048): q cols 0..1023, k cols 1024..2047
                 const unsigned short* __restrict__ vT,   // (B,H,D,T)
                 unsigned short* __restrict__ ob)         // (BT, 1024)
{
  __shared__ unsigned short Ks [64*64];
  __shared__ unsigned short Vts[64*64];
  __shared__ unsigned short Ps [4*16*64];
  int tid = threadIdx.x, lane = tid & 63, wv = tid >> 6;
  int lane15 = lane & 15, laneh = lane >> 4;
  int blk = blockIdx.x;
  int qt = blk & 15, bh = blk >> 4;
  int h = bh & (Hq-1), b = bh >> 4;
  int qrow0 = qt*64 + wv*16;
  size_t tokbase = (size_t)b * Tq;

  // Q fragments (A operand: m=lane15, k=laneh*8 + kk*32), held in regs
  bf16x8 qf[2];
  {
    int t = qrow0 + lane15;
    const unsigned short* qp = qk + (tokbase + t)*2048 + h*64 + laneh*8;
    qf[0] = *(const bf16x8*)(qp);
    qf[1] = *(const bf16x8*)(qp + 32);
  }
  floatx4 oacc[4];
  #pragma unroll
  for (int d = 0; d < 4; d++) oacc[d] = (floatx4){0.f,0.f,0.f,0.f};
  float mrow[4], lrow[4];
  #pragma unroll
  for (int r = 0; r < 4; r++) { mrow[r] = -__builtin_inff(); lrow[r] = 0.f; }

  const unsigned short* Kbase = qk + tokbase*2048 + 1024 + h*64;
  const unsigned short* Vbase = vT + (size_t)bh * Dq * Tq;
  int jend = qt*64;

  for (int j0 = 0; j0 <= jend; j0 += 64) {
    __syncthreads();
    // 64x64 bf16 tile = 512 sixteen-byte segments; row = seg>>3, col = (seg&7)*8
    #pragma unroll
    for (int i = 0; i < 2; i++) {
      int seg = (wv*2+i)*64 + lane;
      int row = seg >> 3, col8 = (seg & 7) * 8;
      gld_lds16(Kbase + (size_t)(j0+row)*2048 + col8, &Ks [(wv*2+i)*512]);
      gld_lds16(Vbase + (size_t)row*Tq + j0 + col8,   &Vts[(wv*2+i)*512]);
    }
    __syncthreads();

    // S = Q @ K^T (per wave: 16 q-rows x 64 kv-cols)
    floatx4 sac[4];
    #pragma unroll
    for (int jt = 0; jt < 4; jt++) {
      sac[jt] = (floatx4){0.f,0.f,0.f,0.f};
      bf16x8 kf0 = *(const bf16x8*)&Ks[(jt*16+lane15)*64 + laneh*8];
      bf16x8 kf1 = *(const bf16x8*)&Ks[(jt*16+lane15)*64 + 32 + laneh*8];
      sac[jt] = __builtin_amdgcn_mfma_f32_16x16x32_bf16(qf[0], kf0, sac[jt], 0, 0, 0);
      sac[jt] = __builtin_amdgcn_mfma_f32_16x16x32_bf16(qf[1], kf1, sac[jt], 0, 0, 0);
    }
    // scale + causal mask (C layout: row=laneh*4+r, col=lane15)
    int trow = qrow0 + laneh*4;
    #pragma unroll
    for (int jt = 0; jt < 4; jt++) {
      int col = j0 + jt*16 + lane15;
      #pragma unroll
      for (int r = 0; r < 4; r++) {
        float s = sac[jt][r] * 0.125f;
        sac[jt][r] = (col <= trow + r) ? s : -__builtin_inff();
      }
    }
    // online softmax
    float alpha[4];
    #pragma unroll
    for (int r = 0; r < 4; r++) {
      float mx = fmaxf(fmaxf(sac[0][r], sac[1][r]), fmaxf(sac[2][r], sac[3][r]));
      #pragma unroll
      for (int s = 1; s < 16; s <<= 1) mx = fmaxf(mx, __shfl_xor(mx, s, 64));
      float mn = fmaxf(mrow[r], mx);
      alpha[r] = expf(mrow[r] - mn);
      float psum = 0.f;
      #pragma unroll
      for (int jt = 0; jt < 4; jt++) {
        float p = expf(sac[jt][r] - mn);
        sac[jt][r] = p;
        psum += p;
      }
      #pragma unroll
      for (int s = 1; s < 16; s <<= 1) psum += __shfl_xor(psum, s, 64);
      lrow[r] = lrow[r] * alpha[r] + psum;
      mrow[r] = mn;
    }
    #pragma unroll
    for (int dt = 0; dt < 4; dt++)
      #pragma unroll
      for (int r = 0; r < 4; r++) oacc[dt][r] *= alpha[r];

    // P: C-layout -> A-layout via LDS
    unsigned short* Pw = &Ps[wv*1024];
    #pragma unroll
    for (int jt = 0; jt < 4; jt++)
      #pragma unroll
      for (int r = 0; r < 4; r++)
        Pw[(laneh*4 + r)*64 + jt*16 + lane15] = f2bf(sac[jt][r]);
    __syncthreads();
    bf16x8 pf0 = *(const bf16x8*)&Ps[wv*1024 + lane15*64 + laneh*8];
    bf16x8 pf1 = *(const bf16x8*)&Ps[wv*1024 + lane15*64 + 32 + laneh*8];
    #pragma unroll
    for (int dt = 0; dt < 4; dt++) {
      bf16x8 vf0 = *(const bf16x8*)&Vts[(dt*16+lane15)*64 + laneh*8];
      bf16x8 vf1 = *(const bf16x8*)&Vts[(dt*16+lane15)*64 + 32 + laneh*8];
      oacc[dt] = __builtin_amdgcn_mfma_f32_16x16x32_bf16(pf0, vf0, oacc[dt], 0, 0, 0);
      oacc[dt] = __builtin_amdgcn_mfma_f32_16x16x32_bf16(pf1, vf1, oacc[dt], 0, 0, 0);
    }
  }
  // epilogue: O /= l
  #pragma unroll
  for (int r = 0; r < 4; r++) {
    int t = qrow0 + laneh*4 + r;
    float inv = 1.f / lrow[r];
    unsigned short* orow = ob + (tokbase + t)*Cq + h*64;
    #pragma unroll
    for (int dt = 0; dt < 4; dt++)
      orow[dt*16 + lane15] = f2bf(oacc[dt][r] * inv);
  }
}

// ---------------- lm head prep: lmWt (64 x 1024 bf16, B-operand rows) + lmWcol (fp32, col 64) ----------------
__global__ __launch_bounds__(256) void lmw_prep_kernel(
    const float* __restrict__ lmW, unsigned short* __restrict__ lmWt,
    float* __restrict__ lmWcol)
{
  int idx = blockIdx.x * 256 + threadIdx.x;   // 65536 threads
  int n = idx & 63, k = idx >> 6;
  lmWt[(size_t)n*Cq + k] = f2bf(lmW[(size_t)k*65 + n]);
  if (idx < Cq) lmWcol[idx] = lmW[(size_t)idx*65 + 64];
}

// ---------------- head: 1 wave per 16 tokens; MFMA logits + fused log-softmax + log-sigmoid(dur) ----------------
__global__ __launch_bounds__(64) void head_mfma_kernel(
    const float* __restrict__ x, const unsigned short* __restrict__ lmWt,
    const float* __restrict__ lmWcol, const float* __restrict__ lmb,
    float* __restrict__ out)
{
  int lane = threadIdx.x;
  int lane15 = lane & 15, laneh = lane >> 4;
  int tok0 = blockIdx.x * 16;

  floatx4 acc[4];
  #pragma unroll
  for (int jt = 0; jt < 4; jt++) acc[jt] = (floatx4){0.f,0.f,0.f,0.f};

  const float* xrow = x + (size_t)(tok0 + lane15) * Cq + laneh*8;
  const unsigned short* brow = lmWt + (size_t)lane15 * Cq + laneh*8;

  for (int k0 = 0; k0 < Cq; k0 += 32) {
    float4 a0 = *(const float4*)(xrow + k0);
    float4 a1 = *(const float4*)(xrow + k0 + 4);
    bf16x8 af;
    af[0] = (__bf16)a0.x; af[1] = (__bf16)a0.y; af[2] = (__bf16)a0.z; af[3] = (__bf16)a0.w;
    af[4] = (__bf16)a1.x; af[5] = (__bf16)a1.y; af[6] = (__bf16)a1.z; af[7] = (__bf16)a1.w;
    #pragma unroll
    for (int jt = 0; jt < 4; jt++) {
      bf16x8 bfv = *(const bf16x8*)(brow + (size_t)jt*16*Cq + k0);
      acc[jt] = __builtin_amdgcn_mfma_f32_16x16x32_bf16(af, bfv, acc[jt], 0, 0, 0);
    }
  }
  // + bias (per output column)
  #pragma unroll
  for (int jt = 0; jt < 4; jt++) {
    float bias = lmb[jt*16 + lane15];
    #pragma unroll
    for (int r = 0; r < 4; r++) acc[jt][r] += bias;
  }
  // log-softmax per token row (C layout: tok = tok0 + laneh*4 + r, col = jt*16 + lane15)
  #pragma unroll
  for (int r = 0; r < 4; r++) {
    float m = fmaxf(fmaxf(acc[0][r], acc[1][r]), fmaxf(acc[2][r], acc[3][r]));
    #pragma unroll
    for (int s = 1; s < 16; s <<= 1) m = fmaxf(m, __shfl_xor(m, s, 64));
    float se = 0.f;
    #pragma unroll
    for (int jt = 0; jt < 4; jt++) se += expf(acc[jt][r] - m);
    #pragma unroll
    for (int s = 1; s < 16; s <<= 1) se += __shfl_xor(se, s, 64);
    float lse = m + logf(se);
    int tok = tok0 + laneh*4 + r;
    float* orow = out + (size_t)tok * 65;
    #pragma unroll
    for (int jt = 0; jt < 4; jt++)
      orow[jt*16 + lane15] = acc[jt][r] - lse;
  }
  // duration logit: exact fp32 dot, 4 lanes per token
  int t = lane >> 2, kq = (lane & 3) * 256;
  const float* xr2 = x + (size_t)(tok0 + t) * Cq + kq;
  const float* wc = lmWcol + kq;
  float s = 0.f;
  #pragma unroll 4
  for (int i = 0; i < 256; i += 4) {
    float4 xv = *(const float4*)(xr2 + i);
    float4 wv = *(const float4*)(wc + i);
    s += xv.x*wv.x + xv.y*wv.y + xv.z*wv.z + xv.w*wv.w;
  }
  s += __shfl_xor(s, 1, 64);
  s += __shfl_xor(s, 2, 64);
  if ((lane & 3) == 0) {
    float z = s + lmb[64];
    float ls = (z >= 0.f) ? -log1pf(expf(-z)) : (z - log1pf(expf(z)));
    out[(size_t)(tok0 + t) * 65 + 64] = ls;
  }
}

extern "C" void kernel_launch(void* const* d_in, const int* in_sizes, int n_in,
                              void* d_out, int out_size, void* d_ws, size_t ws_size,
                              hipStream_t stream) {
  const int*   acts = (const int*)  d_in[0];
  const float* dur  = (const float*)d_in[1];
  const float* emb  = (const float*)d_in[2];
  const float* pos  = (const float*)d_in[3];
  const float* Wq   = (const float*)d_in[4];
  const float* Wk   = (const float*)d_in[5];
  const float* Wv   = (const float*)d_in[6];
  const float* Wo   = (const float*)d_in[7];
  const float* bo   = (const float*)d_in[8];
  const float* W1   = (const float*)d_in[9];
  const float* b1   = (const float*)d_in[10];
  const float* W2   = (const float*)d_in[11];
  const float* b2   = (const float*)d_in[12];
  const float* g1   = (const float*)d_in[13];
  const float* g2   = (const float*)d_in[14];
  const float* lmW  = (const float*)d_in[15];
  const float* lmb  = (const float*)d_in[16];
  float* out = (float*)d_out;
  (void)in_sizes; (void)n_in; (void)out_size; (void)ws_size;

  char* w = (char*)d_ws;
  auto take = [&](size_t bytes) { char* p = w; w += (bytes + 255) & ~(size_t)255; return p; };
  // union region: [qk | vT | ob] is exactly 33.55 MB == m1 (aliased; lifetimes disjoint)
  unsigned short* qk  = (unsigned short*)take((size_t)BT*2048*2);
  unsigned short* vT  = (unsigned short*)take((size_t)Bq*Hq*Dq*Tq*2);
  unsigned short* ob  = (unsigned short*)take((size_t)BT*Cq*2);
  unsigned short* m1  = qk;
  unsigned short* hb  = (unsigned short*)take((size_t)BT*Cq*2);
  float*          x   = (float*)take((size_t)BT*Cq*4);
  unsigned short* wqkvl = (unsigned short*)take((size_t)3072*Cq*2);
  unsigned short* wol   = (unsigned short*)take((size_t)Cq*Cq*2);
  unsigned short* w1l   = (unsigned short*)take((size_t)Fq*Cq*2);
  unsigned short* w2l   = (unsigned short*)take((size_t)Cq*Fq*2);
  unsigned short* lmWt  = (unsigned short*)take((size_t)64*Cq*2);
  float*          lmWcol= (float*)take((size_t)Cq*4);
  float*          part  = (float*)take((size_t)2*BT*Cq*4);   // split-K partials (32 MB)

  dim3 tb(32, 8);
  embed_kernel<<<BT, 256, 0, stream>>>(acts, dur, emb, pos, x);
  lmw_prep_kernel<<<256, 256, 0, stream>>>(lmW, lmWt, lmWcol);

  for (int l = 0; l < Lq; l++) {
    // per-layer weight transposes -> bf16 (N,K) layouts
    transpose_cast_kernel<<<dim3(2,32,16), tb, 0, stream>>>(
        Wq + (size_t)l*Hq*Cq*Dq, wqkvl,               1024, 64, 16, 0, (long long)64*1024);
    transpose_cast_kernel<<<dim3(2,32,16), tb, 0, stream>>>(
        Wk + (size_t)l*Hq*Cq*Dq, wqkvl + 1024*1024,   1024, 64, 16, 0, (long long)64*1024);
    transpose_cast_kernel<<<dim3(2,32,16), tb, 0, stream>>>(
        Wv + (size_t)l*Hq*Cq*Dq, wqkvl + 2048*1024,   1024, 64, 16, 0, (long long)64*1024);
    transpose_cast_kernel<<<dim3(32,32,1), tb, 0, stream>>>(
        Wo + (size_t)l*Cq*Cq,    wol,  1024, 1024, 1, 0, 0);
    transpose_cast_kernel<<<dim3(128,32,1), tb, 0, stream>>>(
        W1 + (size_t)l*Cq*Fq,    w1l,  1024, 4096, 1, 0, 0);
    transpose_cast_kernel<<<dim3(32,128,1), tb, 0, stream>>>(
        W2 + (size_t)l*Fq*Cq,    w2l,  4096, 1024, 1, 0, 0);

    rmsnorm_kernel<<<BT, 256, 0, stream>>>(x, g1 + l*Cq, hb);
    gemm_bt_kernel<0><<<dim3(24,32), 256, 0, stream>>>(
        hb, Cq, wqkvl, Cq, Cq, qk, 2048, vT, nullptr, 0, nullptr);
    attn_kernel<<<Bq*Hq*16, 256, 0, stream>>>(qk, vT, ob);
    gemm_bt_kernel<2><<<dim3(8,32), 256, 0, stream>>>(
        ob, Cq, wol, Cq, Cq, nullptr, 0, nullptr, x, Cq, bo + l*Cq);
    rmsnorm_kernel<<<BT, 256, 0, stream>>>(x, g2 + l*Cq, hb);
    gemm_bt_kernel<1><<<dim3(32,32), 256, 0, stream>>>(
        hb, Cq, w1l, Cq, Cq, m1, Fq, nullptr, nullptr, 0, b1 + l*Fq);
    // FFN2 split-K=2: fp32 partials then fused reduce (+bias, +residual)
    gemm_bt_kernel<3><<<dim3(8,32,2), 256, 0, stream>>>(
        m1, Fq, w2l, Fq, 2048, nullptr, 0, nullptr, part, Cq, nullptr);
    splitk_reduce_kernel<<<BT*Cq/1024, 256, 0, stream>>>(part, x, b2 + l*Cq);
  }
  head_mfma_kernel<<<BT/16, 64, 0, stream>>>(x, lmWt, lmWcol, lmb, out);
}

// Round 6
// 1258.134 us; speedup vs baseline: 1.4291x; 1.1988x over previous
//
#include <hip/hip_runtime.h>

// Problem constants
#define Bq 4
#define Tq 1024
#define Cq 1024
#define Hq 16
#define Dq 64
#define Fq 4096
#define Lq 4
#define BT (Bq*Tq)

typedef __attribute__((ext_vector_type(8))) __bf16 bf16x8;
typedef __attribute__((ext_vector_type(4))) float  floatx4;

__device__ __forceinline__ unsigned short f2bf(float f) {
  unsigned int u = __builtin_bit_cast(unsigned int, f);
  u = (u + 0x7FFFu + ((u >> 16) & 1u)) >> 16;   // RNE
  return (unsigned short)u;
}

// async global->LDS, 16B per lane; lds ptr must be wave-uniform (HW adds lane*16)
__device__ __forceinline__ void gld_lds16(const void* g, void* lds) {
  __builtin_amdgcn_global_load_lds(
      (const __attribute__((address_space(1))) unsigned int*)g,
      (__attribute__((address_space(3))) unsigned int*)lds, 16, 0, 0);
}

// ---------------- embed: x = concat(emb[acts], dur) + pos ----------------
__global__ __launch_bounds__(256) void embed_kernel(
    const int* __restrict__ acts, const float* __restrict__ dur,
    const float* __restrict__ emb, const float* __restrict__ pos,
    float* __restrict__ x)
{
  int tok = blockIdx.x;
  int t = tok & (Tq-1);
  int a = acts[tok];
  const float* er = emb + (size_t)a * (Cq-1);
  const float* pr = pos + (size_t)t * Cq;
  float* xr = x + (size_t)tok * Cq;
  float dv = dur[tok];
  for (int c = threadIdx.x; c < Cq; c += 256) {
    float v = (c < Cq-1) ? er[c] : dv;
    xr[c] = v + pr[c];
  }
}

// ---------------- rmsnorm -> bf16 ----------------
__global__ __launch_bounds__(256) void rmsnorm_kernel(
    const float* __restrict__ x, const float* __restrict__ g,
    unsigned short* __restrict__ h)
{
  int tok = blockIdx.x, tid = threadIdx.x;
  const float4* xr = (const float4*)(x + (size_t)tok * Cq);
  float4 v = xr[tid];
  float ss = v.x*v.x + v.y*v.y + v.z*v.z + v.w*v.w;
  #pragma unroll
  for (int s = 32; s >= 1; s >>= 1) ss += __shfl_xor(ss, s, 64);
  __shared__ float ws4[4];
  if ((tid & 63) == 0) ws4[tid >> 6] = ss;
  __syncthreads();
  float tot = ws4[0] + ws4[1] + ws4[2] + ws4[3];
  float r = rsqrtf(tot * (1.0f/(float)Cq) + 1.1920928955078125e-07f);
  float4 gv = ((const float4*)g)[tid];
  unsigned short o4[4] = { f2bf(v.x*r*gv.x), f2bf(v.y*r*gv.y),
                           f2bf(v.z*r*gv.z), f2bf(v.w*r*gv.w) };
  *(uint2*)(h + (size_t)tok*Cq + tid*4) = *(const uint2*)o4;
}

// ---------------- transpose + cast: in (z batches of R x Cc) f32 -> out (Cc x R) bf16 ----------------
__global__ void transpose_cast_kernel(
    const float* __restrict__ in, unsigned short* __restrict__ out,
    int R, int Cc, int nb2, long long ostr1, long long ostr2)
{
  __shared__ float tile[32][33];
  int c0 = blockIdx.x * 32, r0 = blockIdx.y * 32;
  int tx = threadIdx.x, ty = threadIdx.y;  // 32 x 8
  int z = blockIdx.z;
  const float* ip = in + (size_t)z * R * Cc;
  #pragma unroll
  for (int i = 0; i < 32; i += 8)
    tile[ty+i][tx] = ip[(size_t)(r0+ty+i)*Cc + c0 + tx];
  __syncthreads();
  unsigned short* op = out + (size_t)(z / nb2) * ostr1 + (size_t)(z % nb2) * ostr2;
  #pragma unroll
  for (int i = 0; i < 32; i += 8)
    op[(size_t)(c0+ty+i)*R + r0 + tx] = f2bf(tile[tx][ty+i]);
}

// ---------------- GEMM: C(M,N) = A(M,K) @ Bt(N,K)^T, bf16 in, fp32 acc ----------------
// Single-barrier double-buffered K-loop (R5-verified). LDS 2x(8+8) KB.
// EPI 0: qkv scatter (q,k -> qkbuf bf16 ldc=2048; v -> vT[b][h][d][t])
// EPI 1: bf16 store of gelu(acc + bias)   (tanh-form GELU)
// EPI 2: outF += acc + bias  (fp32 residual add)
// EPI 3: split-K fp32 partial: outF + blockIdx.z*BT*Cq, k-range [z*KS, z*KS+KS)
template <int EPI>
__global__ __launch_bounds__(256)
void gemm_bt_kernel(const unsigned short* __restrict__ A, int lda,
                    const unsigned short* __restrict__ Bt, int ldb,
                    int KS,
                    unsigned short* __restrict__ outB, int ldc,
                    unsigned short* __restrict__ vT,
                    float* __restrict__ outF, int ldf,
                    const float* __restrict__ bias)
{
  __shared__ unsigned short lds_a[2*128*32];
  __shared__ unsigned short lds_b[2*128*32];
  int tid = threadIdx.x;
  int lane = tid & 63, wv = tid >> 6;
  int lane15 = lane & 15, laneh = lane >> 4;
  int m0 = blockIdx.y * 128, n0 = blockIdx.x * 128;
  int wm = wv & 1, wn = wv >> 1;

  floatx4 acc[4][4];
  #pragma unroll
  for (int i = 0; i < 4; i++)
    #pragma unroll
    for (int j = 0; j < 4; j++) acc[i][j] = (floatx4){0.f,0.f,0.f,0.f};

  int seg0 = (wv*2+0)*64 + lane;
  int seg1 = (wv*2+1)*64 + lane;
  int ra0 = seg0 >> 2, ca0 = ((seg0 & 3) ^ (ra0 & 3)) * 8;
  int ra1 = seg1 >> 2, ca1 = ((seg1 & 3) ^ (ra1 & 3)) * 8;
  const unsigned short* a_src0 = A  + (size_t)(m0+ra0)*lda + ca0;
  const unsigned short* a_src1 = A  + (size_t)(m0+ra1)*lda + ca1;
  const unsigned short* b_src0 = Bt + (size_t)(n0+ra0)*ldb + ca0;
  const unsigned short* b_src1 = Bt + (size_t)(n0+ra1)*ldb + ca1;
  unsigned short* a_dst0 = &lds_a[(wv*2+0)*512];
  unsigned short* a_dst1 = &lds_a[(wv*2+1)*512];
  unsigned short* b_dst0 = &lds_b[(wv*2+0)*512];
  unsigned short* b_dst1 = &lds_b[(wv*2+1)*512];

  int sx = (laneh ^ (lane15 & 3)) * 8;

  int kbeg = (EPI == 3) ? blockIdx.z * KS : 0;
  int nIter = KS >> 5;

  auto stage = [&](int k0, int buf) {
    int off = buf * 4096;
    gld_lds16(a_src0 + k0, a_dst0 + off);
    gld_lds16(a_src1 + k0, a_dst1 + off);
    gld_lds16(b_src0 + k0, b_dst0 + off);
    gld_lds16(b_src1 + k0, b_dst1 + off);
  };

  stage(kbeg, 0);
  int cur = 0;
  for (int it = 0; it < nIter; ++it) {
    __syncthreads();
    if (it + 1 < nIter) stage(kbeg + (it+1)*32, cur ^ 1);
    const unsigned short* la = &lds_a[cur*4096];
    const unsigned short* lb = &lds_b[cur*4096];
    bf16x8 af[4], bf[4];
    #pragma unroll
    for (int i = 0; i < 4; i++)
      af[i] = *(const bf16x8*)&la[(wm*64 + i*16 + lane15)*32 + sx];
    #pragma unroll
    for (int j = 0; j < 4; j++)
      bf[j] = *(const bf16x8*)&lb[(wn*64 + j*16 + lane15)*32 + sx];
    #pragma unroll
    for (int i = 0; i < 4; i++)
      #pragma unroll
      for (int j = 0; j < 4; j++)
        acc[i][j] = __builtin_amdgcn_mfma_f32_16x16x32_bf16(af[i], bf[j], acc[i][j], 0, 0, 0);
    cur ^= 1;
  }

  float* outFz = (EPI == 3) ? outF + (size_t)blockIdx.z * BT * Cq : outF;

  #pragma unroll
  for (int i = 0; i < 4; i++) {
    int row = m0 + wm*64 + i*16 + laneh*4;
    #pragma unroll
    for (int j = 0; j < 4; j++) {
      int col = n0 + wn*64 + j*16 + lane15;
      #pragma unroll
      for (int r = 0; r < 4; r++) {
        float v = acc[i][j][r];
        int rr = row + r;
        if constexpr (EPI == 0) {
          if (col < 2048) {
            outB[(size_t)rr*ldc + col] = f2bf(v);
          } else {
            int b = rr >> 10, t = rr & (Tq-1);
            int hd = col - 2048, hh = hd >> 6, d = hd & 63;
            vT[(((size_t)b*Hq + hh)*Dq + d)*Tq + t] = f2bf(v);
          }
        } else if constexpr (EPI == 1) {
          float z = v + bias[col];
          float u = 0.79788456080286536f * (z + 0.044715f * z*z*z);
          float t = 1.f - 2.f / (__expf(2.f*u) + 1.f);
          float gl = 0.5f * z * (1.f + t);
          outB[(size_t)rr*ldc + col] = f2bf(gl);
        } else if constexpr (EPI == 2) {
          outF[(size_t)rr*ldf + col] += v + bias[col];
        } else {
          outFz[(size_t)rr*ldf + col] = v;
        }
      }
    }
  }
}

// ---------------- split-K reduce: x += p0 + p1 + bias ----------------
__global__ __launch_bounds__(256) void splitk_reduce_kernel(
    const float* __restrict__ p, float* __restrict__ x,
    const float* __restrict__ bias)
{
  size_t o = ((size_t)blockIdx.x * 256 + threadIdx.x) * 4;
  float4 a = *(const float4*)(p + o);
  float4 b = *(const float4*)(p + (size_t)BT*Cq + o);
  float4 xv = *(const float4*)(x + o);
  float4 bi = *(const float4*)(bias + (o & (Cq-1)));
  xv.x += a.x + b.x + bi.x;
  xv.y += a.y + b.y + bi.y;
  xv.z += a.z + b.z + bi.z;
  xv.w += a.w + b.w + bi.w;
  *(float4*)(x + o) = xv;
}

// ---------------- flash attention (causal), S^T form ----------------
// Grid: 512 blocks = (bh 0..63) x (pair 0..7); each block does q-tiles p and
// 15-p (17 KV-tile units -> balanced). Per wave: 16 tokens.
// S^T = K @ Q^T  (C layout: row=kv=laneh*4+r, col=token=lane15) -> softmax
// reduction is 15 in-lane ops + 2 shuffles. P^T repacked to B-operand via
// wave-private swizzled LDS (4x ds_write_b64 + 2x ds_read_b128, no barrier).
// O^T = V^T @ P^T accumulated in C layout; vector 8B stores.
// K/V LDS slots XOR-swizzled (slot ^= row&7) -> conflict-free b128 reads.
__global__ __launch_bounds__(256)
void attn_kernel(const unsigned short* __restrict__ qk,   // (BT,2048): q 0..1023, k 1024..2047
                 const unsigned short* __restrict__ vT,   // (B,H,D,T)
                 unsigned short* __restrict__ ob)         // (BT,1024)
{
  __shared__ unsigned short Ks [2][64*64];
  __shared__ unsigned short Vts[2][64*64];
  __shared__ unsigned short Ps [4*16*64];
  int tid = threadIdx.x, lane = tid & 63, wv = tid >> 6;
  int lane15 = lane & 15, laneh = lane >> 4;
  int blk = blockIdx.x;
  int p = blk & 7, bh = blk >> 3;
  int h = bh & (Hq-1), b = bh >> 4;
  size_t tokbase = (size_t)b * Tq;
  const unsigned short* Kbase = qk + tokbase*2048 + 1024 + h*64;
  const unsigned short* Vbase = vT + (size_t)bh * Dq * Tq;

  // swizzled fragment-read offset (row&7 == lane15&7 for all rows used)
  int so  = (laneh ^ (lane15 & 7)) * 8;
  int so32 = so ^ 32;
  unsigned short* Pw = &Ps[wv*1024];
  int pslot = ((laneh >> 1) ^ (lane15 & 7));   // jt adds jt*2 (jt*16>>3)

  auto stage = [&](int j0, int buf) {
    #pragma unroll
    for (int i = 0; i < 2; i++) {
      int seg = (wv*2+i)*64 + lane;
      int row = seg >> 3;
      int col = ((seg & 7) ^ (row & 7)) * 8;
      gld_lds16(Kbase + (size_t)(j0+row)*2048 + col, &Ks [buf][(wv*2+i)*512]);
      gld_lds16(Vbase + (size_t)row*Tq + j0 + col,   &Vts[buf][(wv*2+i)*512]);
    }
  };

  for (int phase = 0; phase < 2; ++phase) {
    int qt = phase ? (15 - p) : p;
    int qrow0 = qt*64 + wv*16;
    // Q as B-operand (n=token=lane15, k=d)
    bf16x8 qf0, qf1;
    {
      const unsigned short* qp = qk + (tokbase + qrow0 + lane15)*2048 + h*64 + laneh*8;
      qf0 = *(const bf16x8*)(qp);
      qf1 = *(const bf16x8*)(qp + 32);
    }
    floatx4 oacc[4];
    #pragma unroll
    for (int d = 0; d < 4; d++) oacc[d] = (floatx4){0.f,0.f,0.f,0.f};
    float mrow = -__builtin_inff(), lrow = 0.f;
    int nT = qt + 1;

    __syncthreads();            // protect LDS bufs from previous phase readers
    stage(0, 0);
    for (int it = 0; it < nT; ++it) {
      __syncthreads();          // drains prefetch (full compute phase to land)
      if (it + 1 < nT) stage((it+1)*64, (it+1) & 1);
      int buf = it & 1;
      int j0 = it*64;

      // S^T = K @ Q^T
      floatx4 sac[4];
      #pragma unroll
      for (int jt = 0; jt < 4; jt++) {
        int row = jt*16 + lane15;
        bf16x8 kf0 = *(const bf16x8*)&Ks[buf][row*64 + so];
        bf16x8 kf1 = *(const bf16x8*)&Ks[buf][row*64 + so32];
        sac[jt] = (floatx4){0.f,0.f,0.f,0.f};
        sac[jt] = __builtin_amdgcn_mfma_f32_16x16x32_bf16(kf0, qf0, sac[jt], 0, 0, 0);
        sac[jt] = __builtin_amdgcn_mfma_f32_16x16x32_bf16(kf1, qf1, sac[jt], 0, 0, 0);
      }
      // scale + causal mask (only diagonal tile needs masking; wave-uniform)
      if (j0 + 63 > qrow0) {
        int tokg = qrow0 + lane15;
        #pragma unroll
        for (int jt = 0; jt < 4; jt++)
          #pragma unroll
          for (int r = 0; r < 4; r++) {
            int kv = j0 + jt*16 + laneh*4 + r;
            sac[jt][r] = (kv <= tokg) ? sac[jt][r] * 0.125f : -__builtin_inff();
          }
      } else {
        #pragma unroll
        for (int jt = 0; jt < 4; jt++)
          #pragma unroll
          for (int r = 0; r < 4; r++) sac[jt][r] *= 0.125f;
      }
      // online softmax: in-lane over 16, cross-lane over laneh group (2 shfl)
      float mx = sac[0][0];
      #pragma unroll
      for (int jt = 0; jt < 4; jt++)
        #pragma unroll
        for (int r = 0; r < 4; r++) mx = fmaxf(mx, sac[jt][r]);
      mx = fmaxf(mx, __shfl_xor(mx, 16, 64));
      mx = fmaxf(mx, __shfl_xor(mx, 32, 64));
      float mn = fmaxf(mrow, mx);
      float alpha = __expf(mrow - mn);
      float psum = 0.f;
      #pragma unroll
      for (int jt = 0; jt < 4; jt++)
        #pragma unroll
        for (int r = 0; r < 4; r++) {
          float pv = __expf(sac[jt][r] - mn);
          sac[jt][r] = pv;
          psum += pv;
        }
      psum += __shfl_xor(psum, 16, 64);
      psum += __shfl_xor(psum, 32, 64);
      lrow = lrow * alpha + psum;
      mrow = mn;
      #pragma unroll
      for (int dt = 0; dt < 4; dt++)
        #pragma unroll
        for (int r = 0; r < 4; r++) oacc[dt][r] *= alpha;

      // P^T: C layout -> B-operand via wave-private swizzled LDS (no barrier)
      #pragma unroll
      for (int jt = 0; jt < 4; jt++) {
        unsigned int p0 = (unsigned int)f2bf(sac[jt][0]) | ((unsigned int)f2bf(sac[jt][1]) << 16);
        unsigned int p1 = (unsigned int)f2bf(sac[jt][2]) | ((unsigned int)f2bf(sac[jt][3]) << 16);
        int slot = (jt*2 + (laneh >> 1)) ^ (lane15 & 7);
        *(uint2*)&Pw[lane15*64 + slot*8 + (laneh & 1)*4] = make_uint2(p0, p1);
      }
      bf16x8 pf0 = *(const bf16x8*)&Pw[lane15*64 + so];
      bf16x8 pf1 = *(const bf16x8*)&Pw[lane15*64 + so32];
      // O^T += V^T @ P^T
      #pragma unroll
      for (int dt = 0; dt < 4; dt++) {
        int row = dt*16 + lane15;
        bf16x8 vf0 = *(const bf16x8*)&Vts[buf][row*64 + so];
        bf16x8 vf1 = *(const bf16x8*)&Vts[buf][row*64 + so32];
        oacc[dt] = __builtin_amdgcn_mfma_f32_16x16x32_bf16(vf0, pf0, oacc[dt], 0, 0, 0);
        oacc[dt] = __builtin_amdgcn_mfma_f32_16x16x32_bf16(vf1, pf1, oacc[dt], 0, 0, 0);
      }
    }
    // epilogue: O /= l; lane owns token=lane15, d = dt*16 + laneh*4 + r
    float inv = 1.f / lrow;
    unsigned short* orow = ob + (tokbase + qrow0 + lane15)*Cq + h*64 + laneh*4;
    #pragma unroll
    for (int dt = 0; dt < 4; dt++) {
      unsigned int u0 = (unsigned int)f2bf(oacc[dt][0]*inv) | ((unsigned int)f2bf(oacc[dt][1]*inv) << 16);
      unsigned int u1 = (unsigned int)f2bf(oacc[dt][2]*inv) | ((unsigned int)f2bf(oacc[dt][3]*inv) << 16);
      *(uint2*)&orow[dt*16] = make_uint2(u0, u1);
    }
  }
}

// ---------------- lm head prep: lmWt (64 x 1024 bf16, B-operand rows) + lmWcol (fp32, col 64) ----------------
__global__ __launch_bounds__(256) void lmw_prep_kernel(
    const float* __restrict__ lmW, unsigned short* __restrict__ lmWt,
    float* __restrict__ lmWcol)
{
  int idx = blockIdx.x * 256 + threadIdx.x;   // 65536 threads
  int n = idx & 63, k = idx >> 6;
  lmWt[(size_t)n*Cq + k] = f2bf(lmW[(size_t)k*65 + n]);
  if (idx < Cq) lmWcol[idx] = lmW[(size_t)idx*65 + 64];
}

// ---------------- head: 1 wave per 16 tokens; MFMA logits + fused log-softmax + log-sigmoid(dur) ----------------
__global__ __launch_bounds__(64) void head_mfma_kernel(
    const float* __restrict__ x, const unsigned short* __restrict__ lmWt,
    const float* __restrict__ lmWcol, const float* __restrict__ lmb,
    float* __restrict__ out)
{
  int lane = threadIdx.x;
  int lane15 = lane & 15, laneh = lane >> 4;
  int tok0 = blockIdx.x * 16;

  floatx4 acc[4];
  #pragma unroll
  for (int jt = 0; jt < 4; jt++) acc[jt] = (floatx4){0.f,0.f,0.f,0.f};

  const float* xrow = x + (size_t)(tok0 + lane15) * Cq + laneh*8;
  const unsigned short* brow = lmWt + (size_t)lane15 * Cq + laneh*8;

  for (int k0 = 0; k0 < Cq; k0 += 32) {
    float4 a0 = *(const float4*)(xrow + k0);
    float4 a1 = *(const float4*)(xrow + k0 + 4);
    bf16x8 af;
    af[0] = (__bf16)a0.x; af[1] = (__bf16)a0.y; af[2] = (__bf16)a0.z; af[3] = (__bf16)a0.w;
    af[4] = (__bf16)a1.x; af[5] = (__bf16)a1.y; af[6] = (__bf16)a1.z; af[7] = (__bf16)a1.w;
    #pragma unroll
    for (int jt = 0; jt < 4; jt++) {
      bf16x8 bfv = *(const bf16x8*)(brow + (size_t)jt*16*Cq + k0);
      acc[jt] = __builtin_amdgcn_mfma_f32_16x16x32_bf16(af, bfv, acc[jt], 0, 0, 0);
    }
  }
  #pragma unroll
  for (int jt = 0; jt < 4; jt++) {
    float bias = lmb[jt*16 + lane15];
    #pragma unroll
    for (int r = 0; r < 4; r++) acc[jt][r] += bias;
  }
  #pragma unroll
  for (int r = 0; r < 4; r++) {
    float m = fmaxf(fmaxf(acc[0][r], acc[1][r]), fmaxf(acc[2][r], acc[3][r]));
    #pragma unroll
    for (int s = 1; s < 16; s <<= 1) m = fmaxf(m, __shfl_xor(m, s, 64));
    float se = 0.f;
    #pragma unroll
    for (int jt = 0; jt < 4; jt++) se += expf(acc[jt][r] - m);
    #pragma unroll
    for (int s = 1; s < 16; s <<= 1) se += __shfl_xor(se, s, 64);
    float lse = m + logf(se);
    int tok = tok0 + laneh*4 + r;
    float* orow = out + (size_t)tok * 65;
    #pragma unroll
    for (int jt = 0; jt < 4; jt++)
      orow[jt*16 + lane15] = acc[jt][r] - lse;
  }
  int t = lane >> 2, kq = (lane & 3) * 256;
  const float* xr2 = x + (size_t)(tok0 + t) * Cq + kq;
  const float* wc = lmWcol + kq;
  float s = 0.f;
  #pragma unroll 4
  for (int i = 0; i < 256; i += 4) {
    float4 xv = *(const float4*)(xr2 + i);
    float4 wv = *(const float4*)(wc + i);
    s += xv.x*wv.x + xv.y*wv.y + xv.z*wv.z + xv.w*wv.w;
  }
  s += __shfl_xor(s, 1, 64);
  s += __shfl_xor(s, 2, 64);
  if ((lane & 3) == 0) {
    float z = s + lmb[64];
    float ls = (z >= 0.f) ? -log1pf(expf(-z)) : (z - log1pf(expf(z)));
    out[(size_t)(tok0 + t) * 65 + 64] = ls;
  }
}

extern "C" void kernel_launch(void* const* d_in, const int* in_sizes, int n_in,
                              void* d_out, int out_size, void* d_ws, size_t ws_size,
                              hipStream_t stream) {
  const int*   acts = (const int*)  d_in[0];
  const float* dur  = (const float*)d_in[1];
  const float* emb  = (const float*)d_in[2];
  const float* pos  = (const float*)d_in[3];
  const float* Wq   = (const float*)d_in[4];
  const float* Wk   = (const float*)d_in[5];
  const float* Wv   = (const float*)d_in[6];
  const float* Wo   = (const float*)d_in[7];
  const float* bo   = (const float*)d_in[8];
  const float* W1   = (const float*)d_in[9];
  const float* b1   = (const float*)d_in[10];
  const float* W2   = (const float*)d_in[11];
  const float* b2   = (const float*)d_in[12];
  const float* g1   = (const float*)d_in[13];
  const float* g2   = (const float*)d_in[14];
  const float* lmW  = (const float*)d_in[15];
  const float* lmb  = (const float*)d_in[16];
  float* out = (float*)d_out;
  (void)in_sizes; (void)n_in; (void)out_size; (void)ws_size;

  char* w = (char*)d_ws;
  auto take = [&](size_t bytes) { char* p = w; w += (bytes + 255) & ~(size_t)255; return p; };
  unsigned short* qk  = (unsigned short*)take((size_t)BT*2048*2);
  unsigned short* vT  = (unsigned short*)take((size_t)Bq*Hq*Dq*Tq*2);
  unsigned short* ob  = (unsigned short*)take((size_t)BT*Cq*2);
  unsigned short* m1  = qk;
  unsigned short* hb  = (unsigned short*)take((size_t)BT*Cq*2);
  float*          x   = (float*)take((size_t)BT*Cq*4);
  unsigned short* wqkvl = (unsigned short*)take((size_t)3072*Cq*2);
  unsigned short* wol   = (unsigned short*)take((size_t)Cq*Cq*2);
  unsigned short* w1l   = (unsigned short*)take((size_t)Fq*Cq*2);
  unsigned short* w2l   = (unsigned short*)take((size_t)Cq*Fq*2);
  unsigned short* lmWt  = (unsigned short*)take((size_t)64*Cq*2);
  float*          lmWcol= (float*)take((size_t)Cq*4);
  float*          part  = (float*)take((size_t)2*BT*Cq*4);   // split-K partials (32 MB)

  dim3 tb(32, 8);
  embed_kernel<<<BT, 256, 0, stream>>>(acts, dur, emb, pos, x);
  lmw_prep_kernel<<<256, 256, 0, stream>>>(lmW, lmWt, lmWcol);

  for (int l = 0; l < Lq; l++) {
    transpose_cast_kernel<<<dim3(2,32,16), tb, 0, stream>>>(
        Wq + (size_t)l*Hq*Cq*Dq, wqkvl,               1024, 64, 16, 0, (long long)64*1024);
    transpose_cast_kernel<<<dim3(2,32,16), tb, 0, stream>>>(
        Wk + (size_t)l*Hq*Cq*Dq, wqkvl + 1024*1024,   1024, 64, 16, 0, (long long)64*1024);
    transpose_cast_kernel<<<dim3(2,32,16), tb, 0, stream>>>(
        Wv + (size_t)l*Hq*Cq*Dq, wqkvl + 2048*1024,   1024, 64, 16, 0, (long long)64*1024);
    transpose_cast_kernel<<<dim3(32,32,1), tb, 0, stream>>>(
        Wo + (size_t)l*Cq*Cq,    wol,  1024, 1024, 1, 0, 0);
    transpose_cast_kernel<<<dim3(128,32,1), tb, 0, stream>>>(
        W1 + (size_t)l*Cq*Fq,    w1l,  1024, 4096, 1, 0, 0);
    transpose_cast_kernel<<<dim3(32,128,1), tb, 0, stream>>>(
        W2 + (size_t)l*Fq*Cq,    w2l,  4096, 1024, 1, 0, 0);

    rmsnorm_kernel<<<BT, 256, 0, stream>>>(x, g1 + l*Cq, hb);
    gemm_bt_kernel<0><<<dim3(24,32), 256, 0, stream>>>(
        hb, Cq, wqkvl, Cq, Cq, qk, 2048, vT, nullptr, 0, nullptr);
    attn_kernel<<<Bq*Hq*8, 256, 0, stream>>>(qk, vT, ob);
    gemm_bt_kernel<2><<<dim3(8,32), 256, 0, stream>>>(
        ob, Cq, wol, Cq, Cq, nullptr, 0, nullptr, x, Cq, bo + l*Cq);
    rmsnorm_kernel<<<BT, 256, 0, stream>>>(x, g2 + l*Cq, hb);
    gemm_bt_kernel<1><<<dim3(32,32), 256, 0, stream>>>(
        hb, Cq, w1l, Cq, Cq, m1, Fq, nullptr, nullptr, 0, b1 + l*Fq);
    gemm_bt_kernel<3><<<dim3(8,32,2), 256, 0, stream>>>(
        m1, Fq, w2l, Fq, 2048, nullptr, 0, nullptr, part, Cq, nullptr);
    splitk_reduce_kernel<<<BT*Cq/1024, 256, 0, stream>>>(part, x, b2 + l*Cq);
  }
  head_mfma_kernel<<<BT/16, 64, 0, stream>>>(x, lmWt, lmWcol, lmb, out);
}

// Round 7
// 1217.718 us; speedup vs baseline: 1.4765x; 1.0332x over previous
//
#include <hip/hip_runtime.h>

// Problem constants
#define Bq 4
#define Tq 1024
#define Cq 1024
#define Hq 16
#define Dq 64
#define Fq 4096
#define Lq 4
#define BT (Bq*Tq)

typedef __attribute__((ext_vector_type(8))) __bf16 bf16x8;
typedef __attribute__((ext_vector_type(4))) float  floatx4;

__device__ __forceinline__ unsigned short f2bf(float f) {
  unsigned int u = __builtin_bit_cast(unsigned int, f);
  u = (u + 0x7FFFu + ((u >> 16) & 1u)) >> 16;   // RNE
  return (unsigned short)u;
}

// async global->LDS, 16B per lane; lds ptr must be wave-uniform (HW adds lane*16)
__device__ __forceinline__ void gld_lds16(const void* g, void* lds) {
  __builtin_amdgcn_global_load_lds(
      (const __attribute__((address_space(1))) unsigned int*)g,
      (__attribute__((address_space(3))) unsigned int*)lds, 16, 0, 0);
}

// partial-drain barrier: require all but the newest 4 global_load_lds done.
// (AITER-style: never vmcnt(0) -> prefetch stays in flight across the barrier)
__device__ __forceinline__ void barrier_vmcnt4() {
  asm volatile("s_waitcnt vmcnt(4)\n\ts_barrier" ::: "memory");
}

// ---------------- embed: x = concat(emb[acts], dur) + pos ----------------
__global__ __launch_bounds__(256) void embed_kernel(
    const int* __restrict__ acts, const float* __restrict__ dur,
    const float* __restrict__ emb, const float* __restrict__ pos,
    float* __restrict__ x)
{
  int tok = blockIdx.x;
  int t = tok & (Tq-1);
  int a = acts[tok];
  const float* er = emb + (size_t)a * (Cq-1);
  const float* pr = pos + (size_t)t * Cq;
  float* xr = x + (size_t)tok * Cq;
  float dv = dur[tok];
  for (int c = threadIdx.x; c < Cq; c += 256) {
    float v = (c < Cq-1) ? er[c] : dv;
    xr[c] = v + pr[c];
  }
}

// ---------------- rmsnorm -> bf16 ----------------
__global__ __launch_bounds__(256) void rmsnorm_kernel(
    const float* __restrict__ x, const float* __restrict__ g,
    unsigned short* __restrict__ h)
{
  int tok = blockIdx.x, tid = threadIdx.x;
  const float4* xr = (const float4*)(x + (size_t)tok * Cq);
  float4 v = xr[tid];
  float ss = v.x*v.x + v.y*v.y + v.z*v.z + v.w*v.w;
  #pragma unroll
  for (int s = 32; s >= 1; s >>= 1) ss += __shfl_xor(ss, s, 64);
  __shared__ float ws4[4];
  if ((tid & 63) == 0) ws4[tid >> 6] = ss;
  __syncthreads();
  float tot = ws4[0] + ws4[1] + ws4[2] + ws4[3];
  float r = rsqrtf(tot * (1.0f/(float)Cq) + 1.1920928955078125e-07f);
  float4 gv = ((const float4*)g)[tid];
  unsigned short o4[4] = { f2bf(v.x*r*gv.x), f2bf(v.y*r*gv.y),
                           f2bf(v.z*r*gv.z), f2bf(v.w*r*gv.w) };
  *(uint2*)(h + (size_t)tok*Cq + tid*4) = *(const uint2*)o4;
}

// ---------------- fused per-layer weight prep: all 6 transposes in 1 launch ----------------
// tiles: [0,3072) qkv (3 x 16 heads x (1024x64)); [3072,4096) Wo (1024x1024);
// [4096,8192) W1 (1024x4096); [8192,12288) W2 (4096x1024)
__global__ void prep_layer_kernel(
    const float* __restrict__ Wq, const float* __restrict__ Wk,
    const float* __restrict__ Wv, const float* __restrict__ Wo,
    const float* __restrict__ W1, const float* __restrict__ W2,
    unsigned short* __restrict__ wqkvl, unsigned short* __restrict__ wol,
    unsigned short* __restrict__ w1l,   unsigned short* __restrict__ w2l)
{
  __shared__ float tile[32][33];
  int z = blockIdx.x;
  const float* in; unsigned short* out;
  int R, Cc, tx, ty;
  if (z < 3072) {
    int i = z >> 10, t = z & 1023;
    int hh = t >> 6, rem = t & 63;
    ty = rem >> 1; tx = rem & 1;
    const float* w = (i == 0) ? Wq : (i == 1) ? Wk : Wv;
    in = w + (size_t)hh * Cq * Dq;
    out = wqkvl + (size_t)i * 1024 * 1024 + (size_t)hh * 64 * 1024;
    R = 1024; Cc = 64;
  } else if (z < 4096) {
    int t = z - 3072;
    tx = t & 31; ty = t >> 5;
    in = Wo; out = wol; R = 1024; Cc = 1024;
  } else if (z < 8192) {
    int t = z - 4096;
    tx = t & 127; ty = t >> 7;
    in = W1; out = w1l; R = 1024; Cc = 4096;
  } else {
    int t = z - 8192;
    tx = t & 31; ty = t >> 5;
    in = W2; out = w2l; R = 4096; Cc = 1024;
  }
  int c0 = tx * 32, r0 = ty * 32;
  int lx = threadIdx.x, ly = threadIdx.y;  // 32 x 8
  #pragma unroll
  for (int i = 0; i < 32; i += 8)
    tile[ly+i][lx] = in[(size_t)(r0+ly+i)*Cc + c0 + lx];
  __syncthreads();
  #pragma unroll
  for (int i = 0; i < 32; i += 8)
    out[(size_t)(c0+ly+i)*R + r0 + lx] = f2bf(tile[lx][ly+i]);
}

// ---------------- GEMM: C(M,N) = A(M,K) @ Bt(N,K)^T, bf16 in, fp32 acc ----------------
// 3-stage LDS pipeline, prefetch distance 2, partial-drain barrier (vmcnt(4)):
// stage(k) is required complete at iter k's barrier while stage(k+1) stays in
// flight (~2 compute phases of latency hiding). 3 bufs make the overwrite
// race-free: buf (k+2)%3 was last read at iter k-1, protected by the barrier.
// EPI 0: qkv scatter; EPI 1: gelu->bf16; EPI 2: fp32 residual add; EPI 3: split-K partial
template <int EPI>
__global__ __launch_bounds__(256)
void gemm_bt_kernel(const unsigned short* __restrict__ A, int lda,
                    const unsigned short* __restrict__ Bt, int ldb,
                    int KS,
                    unsigned short* __restrict__ outB, int ldc,
                    unsigned short* __restrict__ vT,
                    float* __restrict__ outF, int ldf,
                    const float* __restrict__ bias)
{
  __shared__ unsigned short lds_a[3*4096];
  __shared__ unsigned short lds_b[3*4096];
  int tid = threadIdx.x;
  int lane = tid & 63, wv = tid >> 6;
  int lane15 = lane & 15, laneh = lane >> 4;
  int m0 = blockIdx.y * 128, n0 = blockIdx.x * 128;
  int wm = wv & 1, wn = wv >> 1;

  floatx4 acc[4][4];
  #pragma unroll
  for (int i = 0; i < 4; i++)
    #pragma unroll
    for (int j = 0; j < 4; j++) acc[i][j] = (floatx4){0.f,0.f,0.f,0.f};

  int seg0 = (wv*2+0)*64 + lane;
  int seg1 = (wv*2+1)*64 + lane;
  int ra0 = seg0 >> 2, ca0 = ((seg0 & 3) ^ (ra0 & 3)) * 8;
  int ra1 = seg1 >> 2, ca1 = ((seg1 & 3) ^ (ra1 & 3)) * 8;
  const unsigned short* a_src0 = A  + (size_t)(m0+ra0)*lda + ca0;
  const unsigned short* a_src1 = A  + (size_t)(m0+ra1)*lda + ca1;
  const unsigned short* b_src0 = Bt + (size_t)(n0+ra0)*ldb + ca0;
  const unsigned short* b_src1 = Bt + (size_t)(n0+ra1)*ldb + ca1;
  unsigned short* a_dst0 = &lds_a[(wv*2+0)*512];
  unsigned short* a_dst1 = &lds_a[(wv*2+1)*512];
  unsigned short* b_dst0 = &lds_b[(wv*2+0)*512];
  unsigned short* b_dst1 = &lds_b[(wv*2+1)*512];

  int sx = (laneh ^ (lane15 & 3)) * 8;

  int kbeg = (EPI == 3) ? blockIdx.z * KS : 0;
  int nIter = KS >> 5;

  auto stage = [&](int k0, int buf) {
    int off = buf * 4096;
    gld_lds16(a_src0 + k0, a_dst0 + off);
    gld_lds16(a_src1 + k0, a_dst1 + off);
    gld_lds16(b_src0 + k0, b_dst0 + off);
    gld_lds16(b_src1 + k0, b_dst1 + off);
  };

  stage(kbeg, 0);
  stage(kbeg + 32, 1);
  int cb = 0, pb = 2;
  for (int it = 0; it < nIter; ++it) {
    barrier_vmcnt4();                 // stage(it) done; stage(it+1) may remain in flight
    if (it + 2 < nIter) stage(kbeg + (it+2)*32, pb);
    const unsigned short* la = &lds_a[cb*4096];
    const unsigned short* lb = &lds_b[cb*4096];
    bf16x8 af[4], bf[4];
    #pragma unroll
    for (int i = 0; i < 4; i++)
      af[i] = *(const bf16x8*)&la[(wm*64 + i*16 + lane15)*32 + sx];
    #pragma unroll
    for (int j = 0; j < 4; j++)
      bf[j] = *(const bf16x8*)&lb[(wn*64 + j*16 + lane15)*32 + sx];
    #pragma unroll
    for (int i = 0; i < 4; i++)
      #pragma unroll
      for (int j = 0; j < 4; j++)
        acc[i][j] = __builtin_amdgcn_mfma_f32_16x16x32_bf16(af[i], bf[j], acc[i][j], 0, 0, 0);
    cb = (cb == 2) ? 0 : cb + 1;
    pb = (pb == 2) ? 0 : pb + 1;
  }

  float* outFz = (EPI == 3) ? outF + (size_t)blockIdx.z * BT * Cq : outF;

  #pragma unroll
  for (int i = 0; i < 4; i++) {
    int row = m0 + wm*64 + i*16 + laneh*4;
    #pragma unroll
    for (int j = 0; j < 4; j++) {
      int col = n0 + wn*64 + j*16 + lane15;
      #pragma unroll
      for (int r = 0; r < 4; r++) {
        float v = acc[i][j][r];
        int rr = row + r;
        if constexpr (EPI == 0) {
          if (col < 2048) {
            outB[(size_t)rr*ldc + col] = f2bf(v);
          } else {
            int b = rr >> 10, t = rr & (Tq-1);
            int hd = col - 2048, hh = hd >> 6, d = hd & 63;
            vT[(((size_t)b*Hq + hh)*Dq + d)*Tq + t] = f2bf(v);
          }
        } else if constexpr (EPI == 1) {
          float z = v + bias[col];
          float u = 0.79788456080286536f * (z + 0.044715f * z*z*z);
          float t = 1.f - 2.f / (__expf(2.f*u) + 1.f);
          float gl = 0.5f * z * (1.f + t);
          outB[(size_t)rr*ldc + col] = f2bf(gl);
        } else if constexpr (EPI == 2) {
          outF[(size_t)rr*ldf + col] += v + bias[col];
        } else {
          outFz[(size_t)rr*ldf + col] = v;
        }
      }
    }
  }
}

// ---------------- split-K reduce: x += p0 + p1 + bias ----------------
__global__ __launch_bounds__(256) void splitk_reduce_kernel(
    const float* __restrict__ p, float* __restrict__ x,
    const float* __restrict__ bias)
{
  size_t o = ((size_t)blockIdx.x * 256 + threadIdx.x) * 4;
  float4 a = *(const float4*)(p + o);
  float4 b = *(const float4*)(p + (size_t)BT*Cq + o);
  float4 xv = *(const float4*)(x + o);
  float4 bi = *(const float4*)(bias + (o & (Cq-1)));
  xv.x += a.x + b.x + bi.x;
  xv.y += a.y + b.y + bi.y;
  xv.z += a.z + b.z + bi.z;
  xv.w += a.w + b.w + bi.w;
  *(float4*)(x + o) = xv;
}

// ---------------- flash attention (causal), S^T form (R6-verified) ----------------
__global__ __launch_bounds__(256)
void attn_kernel(const unsigned short* __restrict__ qk,   // (BT,2048): q 0..1023, k 1024..2047
                 const unsigned short* __restrict__ vT,   // (B,H,D,T)
                 unsigned short* __restrict__ ob)         // (BT,1024)
{
  __shared__ unsigned short Ks [2][64*64];
  __shared__ unsigned short Vts[2][64*64];
  __shared__ unsigned short Ps [4*16*64];
  int tid = threadIdx.x, lane = tid & 63, wv = tid >> 6;
  int lane15 = lane & 15, laneh = lane >> 4;
  int blk = blockIdx.x;
  int p = blk & 7, bh = blk >> 3;
  int h = bh & (Hq-1), b = bh >> 4;
  size_t tokbase = (size_t)b * Tq;
  const unsigned short* Kbase = qk + tokbase*2048 + 1024 + h*64;
  const unsigned short* Vbase = vT + (size_t)bh * Dq * Tq;

  int so  = (laneh ^ (lane15 & 7)) * 8;
  int so32 = so ^ 32;
  unsigned short* Pw = &Ps[wv*1024];

  auto stage = [&](int j0, int buf) {
    #pragma unroll
    for (int i = 0; i < 2; i++) {
      int seg = (wv*2+i)*64 + lane;
      int row = seg >> 3;
      int col = ((seg & 7) ^ (row & 7)) * 8;
      gld_lds16(Kbase + (size_t)(j0+row)*2048 + col, &Ks [buf][(wv*2+i)*512]);
      gld_lds16(Vbase + (size_t)row*Tq + j0 + col,   &Vts[buf][(wv*2+i)*512]);
    }
  };

  for (int phase = 0; phase < 2; ++phase) {
    int qt = phase ? (15 - p) : p;
    int qrow0 = qt*64 + wv*16;
    bf16x8 qf0, qf1;
    {
      const unsigned short* qp = qk + (tokbase + qrow0 + lane15)*2048 + h*64 + laneh*8;
      qf0 = *(const bf16x8*)(qp);
      qf1 = *(const bf16x8*)(qp + 32);
    }
    floatx4 oacc[4];
    #pragma unroll
    for (int d = 0; d < 4; d++) oacc[d] = (floatx4){0.f,0.f,0.f,0.f};
    float mrow = -__builtin_inff(), lrow = 0.f;
    int nT = qt + 1;

    __syncthreads();
    stage(0, 0);
    for (int it = 0; it < nT; ++it) {
      __syncthreads();
      if (it + 1 < nT) stage((it+1)*64, (it+1) & 1);
      int buf = it & 1;
      int j0 = it*64;

      floatx4 sac[4];
      #pragma unroll
      for (int jt = 0; jt < 4; jt++) {
        int row = jt*16 + lane15;
        bf16x8 kf0 = *(const bf16x8*)&Ks[buf][row*64 + so];
        bf16x8 kf1 = *(const bf16x8*)&Ks[buf][row*64 + so32];
        sac[jt] = (floatx4){0.f,0.f,0.f,0.f};
        sac[jt] = __builtin_amdgcn_mfma_f32_16x16x32_bf16(kf0, qf0, sac[jt], 0, 0, 0);
        sac[jt] = __builtin_amdgcn_mfma_f32_16x16x32_bf16(kf1, qf1, sac[jt], 0, 0, 0);
      }
      if (j0 + 63 > qrow0) {
        int tokg = qrow0 + lane15;
        #pragma unroll
        for (int jt = 0; jt < 4; jt++)
          #pragma unroll
          for (int r = 0; r < 4; r++) {
            int kv = j0 + jt*16 + laneh*4 + r;
            sac[jt][r] = (kv <= tokg) ? sac[jt][r] * 0.125f : -__builtin_inff();
          }
      } else {
        #pragma unroll
        for (int jt = 0; jt < 4; jt++)
          #pragma unroll
          for (int r = 0; r < 4; r++) sac[jt][r] *= 0.125f;
      }
      float mx = sac[0][0];
      #pragma unroll
      for (int jt = 0; jt < 4; jt++)
        #pragma unroll
        for (int r = 0; r < 4; r++) mx = fmaxf(mx, sac[jt][r]);
      mx = fmaxf(mx, __shfl_xor(mx, 16, 64));
      mx = fmaxf(mx, __shfl_xor(mx, 32, 64));
      float mn = fmaxf(mrow, mx);
      float alpha = __expf(mrow - mn);
      float psum = 0.f;
      #pragma unroll
      for (int jt = 0; jt < 4; jt++)
        #pragma unroll
        for (int r = 0; r < 4; r++) {
          float pv = __expf(sac[jt][r] - mn);
          sac[jt][r] = pv;
          psum += pv;
        }
      psum += __shfl_xor(psum, 16, 64);
      psum += __shfl_xor(psum, 32, 64);
      lrow = lrow * alpha + psum;
      mrow = mn;
      #pragma unroll
      for (int dt = 0; dt < 4; dt++)
        #pragma unroll
        for (int r = 0; r < 4; r++) oacc[dt][r] *= alpha;

      #pragma unroll
      for (int jt = 0; jt < 4; jt++) {
        unsigned int p0 = (unsigned int)f2bf(sac[jt][0]) | ((unsigned int)f2bf(sac[jt][1]) << 16);
        unsigned int p1 = (unsigned int)f2bf(sac[jt][2]) | ((unsigned int)f2bf(sac[jt][3]) << 16);
        int slot = (jt*2 + (laneh >> 1)) ^ (lane15 & 7);
        *(uint2*)&Pw[lane15*64 + slot*8 + (laneh & 1)*4] = make_uint2(p0, p1);
      }
      bf16x8 pf0 = *(const bf16x8*)&Pw[lane15*64 + so];
      bf16x8 pf1 = *(const bf16x8*)&Pw[lane15*64 + so32];
      #pragma unroll
      for (int dt = 0; dt < 4; dt++) {
        int row = dt*16 + lane15;
        bf16x8 vf0 = *(const bf16x8*)&Vts[buf][row*64 + so];
        bf16x8 vf1 = *(const bf16x8*)&Vts[buf][row*64 + so32];
        oacc[dt] = __builtin_amdgcn_mfma_f32_16x16x32_bf16(vf0, pf0, oacc[dt], 0, 0, 0);
        oacc[dt] = __builtin_amdgcn_mfma_f32_16x16x32_bf16(vf1, pf1, oacc[dt], 0, 0, 0);
      }
    }
    float inv = 1.f / lrow;
    unsigned short* orow = ob + (tokbase + qrow0 + lane15)*Cq + h*64 + laneh*4;
    #pragma unroll
    for (int dt = 0; dt < 4; dt++) {
      unsigned int u0 = (unsigned int)f2bf(oacc[dt][0]*inv) | ((unsigned int)f2bf(oacc[dt][1]*inv) << 16);
      unsigned int u1 = (unsigned int)f2bf(oacc[dt][2]*inv) | ((unsigned int)f2bf(oacc[dt][3]*inv) << 16);
      *(uint2*)&orow[dt*16] = make_uint2(u0, u1);
    }
  }
}

// ---------------- lm head prep ----------------
__global__ __launch_bounds__(256) void lmw_prep_kernel(
    const float* __restrict__ lmW, unsigned short* __restrict__ lmWt,
    float* __restrict__ lmWcol)
{
  int idx = blockIdx.x * 256 + threadIdx.x;
  int n = idx & 63, k = idx >> 6;
  lmWt[(size_t)n*Cq + k] = f2bf(lmW[(size_t)k*65 + n]);
  if (idx < Cq) lmWcol[idx] = lmW[(size_t)idx*65 + 64];
}

// ---------------- head: MFMA logits + fused log-softmax + log-sigmoid(dur) ----------------
__global__ __launch_bounds__(64) void head_mfma_kernel(
    const float* __restrict__ x, const unsigned short* __restrict__ lmWt,
    const float* __restrict__ lmWcol, const float* __restrict__ lmb,
    float* __restrict__ out)
{
  int lane = threadIdx.x;
  int lane15 = lane & 15, laneh = lane >> 4;
  int tok0 = blockIdx.x * 16;

  floatx4 acc[4];
  #pragma unroll
  for (int jt = 0; jt < 4; jt++) acc[jt] = (floatx4){0.f,0.f,0.f,0.f};

  const float* xrow = x + (size_t)(tok0 + lane15) * Cq + laneh*8;
  const unsigned short* brow = lmWt + (size_t)lane15 * Cq + laneh*8;

  for (int k0 = 0; k0 < Cq; k0 += 32) {
    float4 a0 = *(const float4*)(xrow + k0);
    float4 a1 = *(const float4*)(xrow + k0 + 4);
    bf16x8 af;
    af[0] = (__bf16)a0.x; af[1] = (__bf16)a0.y; af[2] = (__bf16)a0.z; af[3] = (__bf16)a0.w;
    af[4] = (__bf16)a1.x; af[5] = (__bf16)a1.y; af[6] = (__bf16)a1.z; af[7] = (__bf16)a1.w;
    #pragma unroll
    for (int jt = 0; jt < 4; jt++) {
      bf16x8 bfv = *(const bf16x8*)(brow + (size_t)jt*16*Cq + k0);
      acc[jt] = __builtin_amdgcn_mfma_f32_16x16x32_bf16(af, bfv, acc[jt], 0, 0, 0);
    }
  }
  #pragma unroll
  for (int jt = 0; jt < 4; jt++) {
    float bias = lmb[jt*16 + lane15];
    #pragma unroll
    for (int r = 0; r < 4; r++) acc[jt][r] += bias;
  }
  #pragma unroll
  for (int r = 0; r < 4; r++) {
    float m = fmaxf(fmaxf(acc[0][r], acc[1][r]), fmaxf(acc[2][r], acc[3][r]));
    #pragma unroll
    for (int s = 1; s < 16; s <<= 1) m = fmaxf(m, __shfl_xor(m, s, 64));
    float se = 0.f;
    #pragma unroll
    for (int jt = 0; jt < 4; jt++) se += expf(acc[jt][r] - m);
    #pragma unroll
    for (int s = 1; s < 16; s <<= 1) se += __shfl_xor(se, s, 64);
    float lse = m + logf(se);
    int tok = tok0 + laneh*4 + r;
    float* orow = out + (size_t)tok * 65;
    #pragma unroll
    for (int jt = 0; jt < 4; jt++)
      orow[jt*16 + lane15] = acc[jt][r] - lse;
  }
  int t = lane >> 2, kq = (lane & 3) * 256;
  const float* xr2 = x + (size_t)(tok0 + t) * Cq + kq;
  const float* wc = lmWcol + kq;
  float s = 0.f;
  #pragma unroll 4
  for (int i = 0; i < 256; i += 4) {
    float4 xv = *(const float4*)(xr2 + i);
    float4 wv = *(const float4*)(wc + i);
    s += xv.x*wv.x + xv.y*wv.y + xv.z*wv.z + xv.w*wv.w;
  }
  s += __shfl_xor(s, 1, 64);
  s += __shfl_xor(s, 2, 64);
  if ((lane & 3) == 0) {
    float z = s + lmb[64];
    float ls = (z >= 0.f) ? -log1pf(expf(-z)) : (z - log1pf(expf(z)));
    out[(size_t)(tok0 + t) * 65 + 64] = ls;
  }
}

extern "C" void kernel_launch(void* const* d_in, const int* in_sizes, int n_in,
                              void* d_out, int out_size, void* d_ws, size_t ws_size,
                              hipStream_t stream) {
  const int*   acts = (const int*)  d_in[0];
  const float* dur  = (const float*)d_in[1];
  const float* emb  = (const float*)d_in[2];
  const float* pos  = (const float*)d_in[3];
  const float* Wq   = (const float*)d_in[4];
  const float* Wk   = (const float*)d_in[5];
  const float* Wv   = (const float*)d_in[6];
  const float* Wo   = (const float*)d_in[7];
  const float* bo   = (const float*)d_in[8];
  const float* W1   = (const float*)d_in[9];
  const float* b1   = (const float*)d_in[10];
  const float* W2   = (const float*)d_in[11];
  const float* b2   = (const float*)d_in[12];
  const float* g1   = (const float*)d_in[13];
  const float* g2   = (const float*)d_in[14];
  const float* lmW  = (const float*)d_in[15];
  const float* lmb  = (const float*)d_in[16];
  float* out = (float*)d_out;
  (void)in_sizes; (void)n_in; (void)out_size; (void)ws_size;

  char* w = (char*)d_ws;
  auto take = [&](size_t bytes) { char* p = w; w += (bytes + 255) & ~(size_t)255; return p; };
  unsigned short* qk  = (unsigned short*)take((size_t)BT*2048*2);
  unsigned short* vT  = (unsigned short*)take((size_t)Bq*Hq*Dq*Tq*2);
  unsigned short* ob  = (unsigned short*)take((size_t)BT*Cq*2);
  unsigned short* m1  = qk;
  unsigned short* hb  = (unsigned short*)take((size_t)BT*Cq*2);
  float*          x   = (float*)take((size_t)BT*Cq*4);
  unsigned short* wqkvl = (unsigned short*)take((size_t)3072*Cq*2);
  unsigned short* wol   = (unsigned short*)take((size_t)Cq*Cq*2);
  unsigned short* w1l   = (unsigned short*)take((size_t)Fq*Cq*2);
  unsigned short* w2l   = (unsigned short*)take((size_t)Cq*Fq*2);
  unsigned short* lmWt  = (unsigned short*)take((size_t)64*Cq*2);
  float*          lmWcol= (float*)take((size_t)Cq*4);
  float*          part  = (float*)take((size_t)2*BT*Cq*4);   // split-K partials (32 MB)

  dim3 tb(32, 8);
  embed_kernel<<<BT, 256, 0, stream>>>(acts, dur, emb, pos, x);
  lmw_prep_kernel<<<256, 256, 0, stream>>>(lmW, lmWt, lmWcol);

  for (int l = 0; l < Lq; l++) {
    prep_layer_kernel<<<12288, tb, 0, stream>>>(
        Wq + (size_t)l*Hq*Cq*Dq, Wk + (size_t)l*Hq*Cq*Dq, Wv + (size_t)l*Hq*Cq*Dq,
        Wo + (size_t)l*Cq*Cq, W1 + (size_t)l*Cq*Fq, W2 + (size_t)l*Fq*Cq,
        wqkvl, wol, w1l, w2l);

    rmsnorm_kernel<<<BT, 256, 0, stream>>>(x, g1 + l*Cq, hb);
    gemm_bt_kernel<0><<<dim3(24,32), 256, 0, stream>>>(
        hb, Cq, wqkvl, Cq, Cq, qk, 2048, vT, nullptr, 0, nullptr);
    attn_kernel<<<Bq*Hq*8, 256, 0, stream>>>(qk, vT, ob);
    gemm_bt_kernel<2><<<dim3(8,32), 256, 0, stream>>>(
        ob, Cq, wol, Cq, Cq, nullptr, 0, nullptr, x, Cq, bo + l*Cq);
    rmsnorm_kernel<<<BT, 256, 0, stream>>>(x, g2 + l*Cq, hb);
    gemm_bt_kernel<1><<<dim3(32,32), 256, 0, stream>>>(
        hb, Cq, w1l, Cq, Cq, m1, Fq, nullptr, nullptr, 0, b1 + l*Fq);
    gemm_bt_kernel<3><<<dim3(8,32,2), 256, 0, stream>>>(
        m1, Fq, w2l, Fq, 2048, nullptr, 0, nullptr, part, Cq, nullptr);
    splitk_reduce_kernel<<<BT*Cq/1024, 256, 0, stream>>>(part, x, b2 + l*Cq);
  }
  head_mfma_kernel<<<BT/16, 64, 0, stream>>>(x, lmWt, lmWcol, lmb, out);
}